// Round 7
// baseline (2781.948 us; speedup 1.0000x reference)
//
#include <hip/hip_runtime.h>
#include <math.h>

#define NPROTO 8
#define KV_NCH 4
#define MSG_NCH 8

typedef __attribute__((ext_vector_type(8))) short short8;
typedef __attribute__((ext_vector_type(4))) float floatx4;

static __device__ __forceinline__ ushort f2b(float f) {
    unsigned u = __builtin_bit_cast(unsigned, f);
    unsigned r = (u + 0x7fffu + ((u >> 16) & 1u)) >> 16;
    return (ushort)r;
}

static __device__ __forceinline__ float elu1(float v) {
    return v > 0.f ? v + 1.f : __expf(v);
}

// async 16B global -> LDS (linear dest: wave base + lane*16B)
#define GLOAD16(gp, lp) __builtin_amdgcn_global_load_lds( \
    (const __attribute__((address_space(1))) void*)(gp),  \
    (__attribute__((address_space(3))) void*)(lp), 16, 0, 0)

// drain staging loads + retire LDS ops, then barrier (memory-fenced)
#define WAIT_BAR() asm volatile("s_waitcnt vmcnt(0) lgkmcnt(0)\n\ts_barrier" ::: "memory")

// ---------------- prototype projection / argmax-class kernel ----------------
__global__ __launch_bounds__(256) void lft_class_kernel(
    const float* __restrict__ f0wo, const float* __restrict__ f1wo,
    const int* __restrict__ mask0, const int* __restrict__ mask1,
    const float* __restrict__ proto,
    float* out, int* cls0, int* cls1)
{
    __shared__ float pr[2048];          // proto [8][256]
    __shared__ float tile[256][64];     // [token][ch], swizzled in ch
    int t = threadIdx.x;
    *(float4*)&pr[t * 4]        = *(const float4*)&proto[t * 4];
    *(float4*)&pr[1024 + t * 4] = *(const float4*)&proto[1024 + t * 4];
    long tok0 = (long)blockIdx.x * 256;
    const float* fsrc; const int* msrc; float* fpout; float* clsout; int* clsarr; long tbase;
    if (tok0 < 38400) {
        tbase = tok0; fsrc = f0wo; msrc = mask0;
        fpout = out + 19737600L; clsout = out + 19660800L; clsarr = cls0;
    } else {
        tbase = tok0 - 38400; fsrc = f1wo; msrc = mask1;
        fpout = out + 20044800L; clsout = out + 19699200L; clsarr = cls1;
    }
    float s[NPROTO] = {};
    int r0 = t >> 4;            // 0..15
    int c4 = (t & 15) << 2;     // 0..60
    for (int ct = 0; ct < 4; ct++) {
        __syncthreads();
#pragma unroll
        for (int rr = 0; rr < 16; rr++) {
            int row = rr * 16 + r0;
            float4 v = *(const float4*)&fsrc[(tbase + row) * 256 + ct * 64 + c4];
            *(float4*)&tile[row][c4 ^ ((row & 7) << 2)] = v;
        }
        __syncthreads();
#pragma unroll
        for (int cc = 0; cc < 16; cc++) {
            float4 f = *(const float4*)&tile[t][(cc << 2) ^ ((t & 7) << 2)];
#pragma unroll
            for (int p = 0; p < NPROTO; p++) {
                float4 pv = *(const float4*)&pr[p * 256 + ct * 64 + (cc << 2)];
                s[p] += f.x * pv.x + f.y * pv.y + f.z * pv.z + f.w * pv.w;
            }
        }
    }
    long tok = tbase + t;
    int best = 0; float bv = s[0];
#pragma unroll
    for (int p = 1; p < NPROTO; p++) { if (s[p] > bv) { bv = s[p]; best = p; } }
#pragma unroll
    for (int p = 0; p < NPROTO; p++) fpout[tok * 8 + p] = s[p];
    clsout[tok] = (float)best;
    clsarr[tok] = msrc[tok] ? best : -1;
}

// ---------------- counting sort of tokens by (batch,class) -------------------
__global__ __launch_bounds__(256) void lft_sort_kernel(
    const int* __restrict__ cls0, const int* __restrict__ cls1,
    int* tl0, int* tl1, int* meta)
{
    int g = blockIdx.x; int L = g >> 3, b = g & 7;
    const int* cls = (L ? cls1 : cls0) + b * 4800;
    int* tl = (L ? tl1 : tl0) + b * 4800;
    int* mt = meta + (L * 8 + b) * 16;
    __shared__ int cnt[8], base[8], pos[8];
    int t = threadIdx.x;
    if (t < 8) cnt[t] = 0;
    __syncthreads();
    for (int tok = t; tok < 4800; tok += 256) {
        int c = cls[tok];
        if (c >= 0) atomicAdd(&cnt[c], 1);
    }
    __syncthreads();
    if (t == 0) {
        int s = 0;
        for (int c = 0; c < 8; c++) { base[c] = s; pos[c] = s; s += cnt[c]; }
    }
    __syncthreads();
    if (t < 8) { mt[t * 2] = base[t]; mt[t * 2 + 1] = cnt[t]; }
    for (int tok = t; tok < 4800; tok += 256) {
        int c = cls[tok];
        if (c >= 0) { int p = atomicAdd(&pos[c], 1); tl[p] = tok; }
    }
}

// ---------------- weight convert + transpose: Wt[n*K+k] = bf16(W[k*N+n]) ----
__global__ __launch_bounds__(256) void lft_wconv_kernel(
    const float* W0, const float* W1p, const float* W2p, const float* W3p,
    int K, int N, int nTypes, ushort* dst)
{
    int z = blockIdx.z;
    int li = z / nTypes, mi = z % nTypes;
    const float* srcs[4] = {W0, W1p, W2p, W3p};
    const float* src = srcs[mi] + (size_t)li * K * N;
    ushort* outp = dst + (size_t)z * K * N;
    __shared__ float tile[32][33];
    int k0 = blockIdx.x * 32, n0 = blockIdx.y * 32;
    int t = threadIdx.x;
    int r = t >> 3, c4 = (t & 7) << 2;
    float4 v = *(const float4*)&src[(size_t)(k0 + r) * N + n0 + c4];
    tile[r][c4] = v.x; tile[r][c4 + 1] = v.y; tile[r][c4 + 2] = v.z; tile[r][c4 + 3] = v.w;
    __syncthreads();
    ushort4 o;
    o.x = f2b(tile[c4 + 0][r]);
    o.y = f2b(tile[c4 + 1][r]);
    o.z = f2b(tile[c4 + 2][r]);
    o.w = f2b(tile[c4 + 3][r]);
    *(ushort4*)&outp[(size_t)(n0 + r) * K + k0 + c4] = o;
}

// ---------------- bf16 cast of feat0/feat1 (shadows only, nt stores) --------
__global__ __launch_bounds__(256) void lft_cast_kernel(
    const float* __restrict__ f0, const float* __restrict__ f1,
    ushort* fab, ushort* fbb)
{
    long idx = ((long)blockIdx.x * 256 + threadIdx.x) * 4;
    const float* src; ushort* db; long o;
    if (idx < 9830400L) { src = f0; db = fab; o = idx; }
    else                { src = f1; db = fbb; o = idx - 9830400L; }
    float4 v = *(const float4*)&src[o];
    ushort4 u; u.x = f2b(v.x); u.y = f2b(v.y); u.z = f2b(v.z); u.w = f2b(v.w);
    __builtin_nontemporal_store(__builtin_bit_cast(unsigned long long, u),
                                (unsigned long long*)&db[o]);
}

// =============================================================================
// GEMM core notes (R5): A staged via global_load_lds in BK=64 chunks
// ([rows][64] bf16, 128B/row contiguous -> good DRAM paging), XOR-swizzled
// 16B groups (slot g holds global chunk g^(row&7)); B (weights, L2-resident)
// loaded straight into MFMA fragment registers - no LDS, no extra barriers.
// All streaming C writes nontemporal so weights stay L2-resident.
// XCD-aware block swizzle: each XCD gets a contiguous m-range (n fastest).
// =============================================================================

// ---------------- bf16 MFMA GEMM: C[38400,N] = act([A0|A1] @ Wt^T) ----------
// 256 thr, 128x128 tile, 4 waves (2x2).
// act: 0 none, 1 elu+1, 2 relu  -> Cf (fp32, stride N) / Cb (bf16, stride N)
// act 3: qkv-fused N=768: col<256 -> Cb=q bf16 elu ; <512 -> Cf=phi_k fp32 ;
//        else Cv=v fp32.   act 4: kv-fused N=512: Cf=phi_k ; Cv=v.
__global__ __launch_bounds__(256, 3) void lft_mfma_gemm(
    const ushort* __restrict__ A0, const ushort* __restrict__ A1, int kSplit,
    const ushort* __restrict__ Wt,
    float* Cf, ushort* Cb, float* Cv, int N, int K, int act)
{
    __shared__ ushort As[2][128 * 64];
    int t = threadIdx.x;
    int G = gridDim.x * gridDim.y;
    int orig = blockIdx.y * gridDim.x + blockIdx.x;
    int id = ((orig & 7) * (G >> 3)) + (orig >> 3);   // G % 8 == 0
    int bn = id % gridDim.x;
    long m0 = (long)(id / gridDim.x) << 7;
    int n0 = bn << 7;
    int wv = t >> 6, lane = t & 63;
    int wm = wv >> 1, wn = wv & 1;
    int l16 = lane & 15, quad = lane >> 4;
    int sr = lane >> 3;            // 0..7 row-within-instr
    int sc = (lane & 7) ^ sr;      // swizzled source 16B chunk
    floatx4 acc[4][4] = {};

    auto stage = [&](int buf, int k0) {   // A chunk: 128 rows x 64 cols
        const ushort* Asrc; int kcol, ldA;
        if (k0 < kSplit) { Asrc = A0; kcol = k0;          ldA = kSplit; }
        else             { Asrc = A1; kcol = k0 - kSplit; ldA = K - kSplit; }
#pragma unroll
        for (int j = 0; j < 4; j++) {
            int rb = wv * 32 + j * 8;
            GLOAD16(&Asrc[(m0 + rb + sr) * ldA + kcol + sc * 8], &As[buf][rb * 64]);
        }
    };

    auto compute = [&](int buf, int c) {
        const ushort* Ab = &As[buf][0];
#pragma unroll
        for (int kk = 0; kk < 2; kk++) {
            short8 af[4], bfr[4];
#pragma unroll
            for (int i = 0; i < 4; i++) {
                int rA = wm * 64 + i * 16 + l16;
                af[i] = *(const short8*)&Ab[rA * 64 + ((((kk << 2) + quad) ^ (rA & 7)) << 3)];
                int rB = n0 + wn * 64 + i * 16 + l16;
                bfr[i] = *(const short8*)&Wt[(size_t)rB * K + (c << 6) + (kk << 5) + quad * 8];
            }
            __builtin_amdgcn_s_setprio(1);
#pragma unroll
            for (int i = 0; i < 4; i++)
#pragma unroll
                for (int j = 0; j < 4; j++)
                    acc[i][j] = __builtin_amdgcn_mfma_f32_16x16x32_bf16(af[i], bfr[j], acc[i][j], 0, 0, 0);
            __builtin_amdgcn_s_setprio(0);
        }
    };

    int nc = K >> 6;               // 4 or 8 chunks
    stage(0, 0);
    WAIT_BAR();
    int cur = 0;
    for (int c = 0; c < nc; ++c) {
        if (c + 1 < nc) stage(cur ^ 1, (c + 1) << 6);
        compute(cur, c);
        if (c + 1 < nc) { WAIT_BAR(); cur ^= 1; }
    }

#pragma unroll
    for (int i = 0; i < 4; i++) {
#pragma unroll
        for (int j = 0; j < 4; j++) {
#pragma unroll
            for (int r = 0; r < 4; r++) {
                float v = acc[i][j][r];
                long row = m0 + wm * 64 + i * 16 + quad * 4 + r;
                int col = n0 + wn * 64 + j * 16 + l16;
                if (act == 3) {
                    if (col < 256)      __builtin_nontemporal_store(f2b(elu1(v)), &Cb[row * 256 + col]);
                    else if (col < 512) __builtin_nontemporal_store(elu1(v), &Cf[row * 256 + col - 256]);
                    else                __builtin_nontemporal_store(v, &Cv[row * 256 + col - 512]);
                } else if (act == 4) {
                    if (col < 256) __builtin_nontemporal_store(elu1(v), &Cf[row * 256 + col]);
                    else           __builtin_nontemporal_store(v, &Cv[row * 256 + col - 256]);
                } else {
                    if (act == 1)      v = elu1(v);
                    else if (act == 2) v = fmaxf(v, 0.f);
                    if (Cf) __builtin_nontemporal_store(v, &Cf[row * N + col]);
                    if (Cb) __builtin_nontemporal_store(f2b(v), &Cb[row * N + col]);
                }
            }
        }
    }
}

// ---------------- fused GEMM (N=256) + row-LayerNorm epilogue ----------------
// 256 thr, M=64 tile (grid 600), wave w owns cols [64w,+64). A in LDS (BK=64
// chunks), B (256xK weights) from L2 to registers.
__global__ __launch_bounds__(256, 3) void lft_gemm_ln(
    const ushort* __restrict__ A0, const ushort* __restrict__ A1, int kSplit,
    const ushort* __restrict__ Wt, int K,
    const float* __restrict__ g, const float* __restrict__ bb,
    const float* __restrict__ resid, const int* __restrict__ cls,
    float* outF, ushort* __restrict__ outB)
{
    __shared__ ushort As[2][64 * 64];
    __shared__ float psum[4][64], psq[4][64];
    int t = threadIdx.x;
    int orig = blockIdx.x;
    int G = gridDim.x;
    int id = ((orig & 7) * (G >> 3)) + (orig >> 3);   // 600 % 8 == 0
    long m0 = (long)id << 6;
    int wv = t >> 6, lane = t & 63;
    int l16 = lane & 15, quad = lane >> 4;
    int sr = lane >> 3;
    int sc = (lane & 7) ^ sr;
    floatx4 acc[4][4] = {};

    float gj[4], bj[4];
#pragma unroll
    for (int j = 0; j < 4; j++) {
        int col = wv * 64 + j * 16 + l16;
        gj[j] = g[col]; bj[j] = bb[col];
    }

    auto stage = [&](int buf, int k0) {   // A chunk: 64 rows x 64 cols
        const ushort* Asrc; int kcol, ldA;
        if (k0 < kSplit) { Asrc = A0; kcol = k0;          ldA = kSplit; }
        else             { Asrc = A1; kcol = k0 - kSplit; ldA = K - kSplit; }
#pragma unroll
        for (int j = 0; j < 2; j++) {
            int rb = wv * 16 + j * 8;
            GLOAD16(&Asrc[(m0 + rb + sr) * ldA + kcol + sc * 8], &As[buf][rb * 64]);
        }
    };

    auto compute = [&](int buf, int c) {
        const ushort* Ab = &As[buf][0];
#pragma unroll
        for (int kk = 0; kk < 2; kk++) {
            short8 af[4], bfr[4];
#pragma unroll
            for (int i = 0; i < 4; i++) {
                int rA = i * 16 + l16;
                af[i] = *(const short8*)&Ab[rA * 64 + ((((kk << 2) + quad) ^ (rA & 7)) << 3)];
                int rB = wv * 64 + i * 16 + l16;
                bfr[i] = *(const short8*)&Wt[(size_t)rB * K + (c << 6) + (kk << 5) + quad * 8];
            }
            __builtin_amdgcn_s_setprio(1);
#pragma unroll
            for (int i = 0; i < 4; i++)
#pragma unroll
                for (int j = 0; j < 4; j++)
                    acc[i][j] = __builtin_amdgcn_mfma_f32_16x16x32_bf16(af[i], bfr[j], acc[i][j], 0, 0, 0);
            __builtin_amdgcn_s_setprio(0);
        }
    };

    int nc = K >> 6;
    stage(0, 0);
    WAIT_BAR();
    int cur = 0;
    for (int c = 0; c < nc; ++c) {
        if (c + 1 < nc) stage(cur ^ 1, (c + 1) << 6);
        compute(cur, c);
        if (c + 1 < nc) { WAIT_BAR(); cur ^= 1; }
    }

    // per-row partial sums (this wave's 64 cols) -> LDS
#pragma unroll
    for (int i = 0; i < 4; i++) {
#pragma unroll
        for (int r = 0; r < 4; r++) {
            float s = 0.f, q = 0.f;
#pragma unroll
            for (int j = 0; j < 4; j++) { float v = acc[i][j][r]; s += v; q += v * v; }
#pragma unroll
            for (int o = 8; o >= 1; o >>= 1) {
                s += __shfl_xor(s, o, 64);
                q += __shfl_xor(q, o, 64);
            }
            if (l16 == 0) {
                int row = i * 16 + quad * 4 + r;
                psum[wv][row] = s; psq[wv][row] = q;
            }
        }
    }
    __syncthreads();
    if (t < 64) {
        float s = psum[0][t] + psum[1][t] + psum[2][t] + psum[3][t];
        float q = psq[0][t] + psq[1][t] + psq[2][t] + psq[3][t];
        float mean = s * (1.0f / 256.0f);
        float var = q * (1.0f / 256.0f) - mean * mean;
        psum[0][t] = mean;
        psq[0][t] = rsqrtf(var + 1e-5f);
    }
    __syncthreads();
#pragma unroll
    for (int i = 0; i < 4; i++) {
#pragma unroll
        for (int r = 0; r < 4; r++) {
            int rloc = i * 16 + quad * 4 + r;
            long grow = m0 + rloc;
            float mean = psum[0][rloc], rstd = psq[0][rloc];
            int cv = cls ? cls[grow] : 0;
#pragma unroll
            for (int j = 0; j < 4; j++) {
                int col = wv * 64 + j * 16 + l16;
                float y = (acc[i][j][r] - mean) * rstd * gj[j] + bj[j];
                if (resid) {
                    float xr = __builtin_nontemporal_load(&resid[grow * 256 + col]);
                    y = (cv >= 0) ? xr + y : xr;
                }
                if (outF) __builtin_nontemporal_store(y, &outF[grow * 256 + col]);
                __builtin_nontemporal_store(f2b(y), &outB[grow * 256 + col]);
            }
        }
    }
}

// ---------------- per-class KV / Ksum reduction (SRC-side token lists) --------
__global__ __launch_bounds__(256) void lft_kv_kernel(
    const float* __restrict__ phik, const float* __restrict__ vmat,
    const int* __restrict__ tlist, const int* __restrict__ meta,
    float* kv, float* ksum)
{
    int chunk = blockIdx.x, c = blockIdx.y;
    int b = blockIdx.z >> 3, h = blockIdx.z & 7;
    int off = meta[(b * 8 + c) * 2], n = meta[(b * 8 + c) * 2 + 1];
    int per = (n + KV_NCH - 1) / KV_NCH;
    int s0 = chunk * per;
    int s1 = min(s0 + per, n);
    if (s0 >= s1) return;
    const int* tl = tlist + b * 4800 + off;
    int t = threadIdx.x;
    __shared__ float kb[8][32];
    __shared__ float vb[8][32];
    int od = t >> 3, oe = (t & 7) << 2;
    int lt = t >> 5, ld = t & 31;
    float a0 = 0.f, a1 = 0.f, a2 = 0.f, a3 = 0.f, ak = 0.f;
    for (int s = s0; s < s1; s += 8) {
        float kval = 0.f, vval = 0.f;
        if (s + lt < s1) {
            int tok = tl[s + lt];
            long bse = ((long)b * 4800 + tok) * 256 + h * 32 + ld;
            kval = phik[bse];
            vval = vmat[bse];
        }
        __syncthreads();
        kb[lt][ld] = kval;
        vb[lt][ld] = vval;
        __syncthreads();
#pragma unroll
        for (int j = 0; j < 8; j++) {
            float kd = kb[j][od];
            float4 vv = *(const float4*)&vb[j][oe];
            a0 += kd * vv.x; a1 += kd * vv.y; a2 += kd * vv.z; a3 += kd * vv.w;
            ak += kd;
        }
    }
    float* dst = kv + (((long)(b * NPROTO + c) * 8 + h) << 10) + od * 32 + oe;
    atomicAdd(dst + 0, a0);
    atomicAdd(dst + 1, a1);
    atomicAdd(dst + 2, a2);
    atomicAdd(dst + 3, a3);
    if ((t & 7) == 0)
        atomicAdd(ksum + (((long)(b * NPROTO + c) * 8 + h) << 5) + od, ak);
}

// ---------------- kv fp32 [d][e] + ksum → bf16 B-layout [e'][d], e'<48 -------
__global__ __launch_bounds__(256) void lft_kvconv_kernel(
    const float* __restrict__ kvb, const float* __restrict__ ksb,
    ushort* __restrict__ kvt)
{
    int bc = blockIdx.x;          // b*8+c
    int t = threadIdx.x;
    int h = t >> 5, d = t & 31;
    const float* kvsrc = kvb + ((long)bc * 8 + h) * 1024;
    const float* kssrc = ksb + ((long)bc * 8 + h) * 32;
    ushort* dst = kvt + ((long)bc * 8 + h) * 1536;
#pragma unroll
    for (int e = 0; e < 32; e++) dst[e * 32 + d] = f2b(kvsrc[d * 32 + e]);
    dst[32 * 32 + d] = f2b(kssrc[d]);
#pragma unroll
    for (int e = 33; e < 48; e++) dst[e * 32 + d] = 0;
}

// ---------------- msg via MFMA over X-SIDE class-sorted lists ----------------
__global__ __launch_bounds__(256) void lft_msg_kernel(
    const ushort* __restrict__ pq, const ushort* __restrict__ kvt,
    const int* __restrict__ tlist, const int* __restrict__ meta,
    ushort* __restrict__ msg)
{
    int chunk = blockIdx.x, c = blockIdx.y, b = blockIdx.z;
    int off = meta[(b * 8 + c) * 2], n = meta[(b * 8 + c) * 2 + 1];
    int per = (n + MSG_NCH - 1) / MSG_NCH;
    int s0 = chunk * per, s1 = min(s0 + per, n);
    if (s0 >= s1) return;
    const int* tl = tlist + b * 4800 + off;
    int t = threadIdx.x;
    int wave = t >> 6, lane = t & 63;
    int l16 = lane & 15, quad = lane >> 4;
    int bc = b * 8 + c;
    short8 bfr[2][3];
#pragma unroll
    for (int hh = 0; hh < 2; hh++) {
        int h = wave * 2 + hh;
        const ushort* kb = kvt + ((long)bc * 8 + h) * 1536;
#pragma unroll
        for (int nt = 0; nt < 3; nt++)
            bfr[hh][nt] = *(const short8*)&kb[(nt * 16 + l16) * 32 + quad * 8];
    }
    for (int s = s0; s < s1; s += 16) {
        int ia = min(s + l16, s1 - 1);
        int tokA = tl[ia];
        long rowA = (long)b * 4800 + tokA;
#pragma unroll
        for (int hh = 0; hh < 2; hh++) {
            int h = wave * 2 + hh;
            short8 a = *(const short8*)&pq[rowA * 256 + h * 32 + quad * 8];
            floatx4 n0 = {}, n1 = {}, dd = {};
            n0 = __builtin_amdgcn_mfma_f32_16x16x32_bf16(a, bfr[hh][0], n0, 0, 0, 0);
            n1 = __builtin_amdgcn_mfma_f32_16x16x32_bf16(a, bfr[hh][1], n1, 0, 0, 0);
            dd = __builtin_amdgcn_mfma_f32_16x16x32_bf16(a, bfr[hh][2], dd, 0, 0, 0);
#pragma unroll
            for (int r = 0; r < 4; r++) {
                int rowi = s + quad * 4 + r;
                float den = __shfl(dd[r], lane & 48, 64);
                float inv = 1.f / (den + 1e-6f);
                int tokr = __shfl(tokA, quad * 4 + r, 64);
                if (rowi < s1) {
                    long base = ((long)b * 4800 + tokr) * 256 + h * 32;
                    msg[base + l16]      = f2b(n0[r] * inv);
                    msg[base + 16 + l16] = f2b(n1[r] * inv);
                }
            }
        }
    }
}

extern "C" void kernel_launch(void* const* d_in, const int* in_sizes, int n_in,
                              void* d_out, int out_size, void* d_ws, size_t ws_size,
                              hipStream_t stream)
{
    (void)in_sizes; (void)n_in; (void)out_size; (void)ws_size;
    const float* feat0 = (const float*)d_in[0];
    const float* feat1 = (const float*)d_in[1];
    const int*   mask0 = (const int*)d_in[2];
    const int*   mask1 = (const int*)d_in[3];
    const float* f0wo  = (const float*)d_in[4];
    const float* f1wo  = (const float*)d_in[5];
    const float* proto = (const float*)d_in[6];
    const float* Wq = (const float*)d_in[7];
    const float* Wk = (const float*)d_in[8];
    const float* Wv = (const float*)d_in[9];
    const float* Wm = (const float*)d_in[10];
    const float* W1 = (const float*)d_in[11];
    const float* W2 = (const float*)d_in[12];
    const float* g1 = (const float*)d_in[13];
    const float* b1 = (const float*)d_in[14];
    const float* g2 = (const float*)d_in[15];
    const float* b2 = (const float*)d_in[16];
    float* out = (float*)d_out;
    float* ws = (float*)d_ws;

    // ---- workspace layout (unchanged) ----
    const long FSZ = 9830400L;           // 8*4800*256
    float* fa   = ws;
    float* fb   = ws + FSZ;
    float* kbuf = ws + 2 * FSZ;          // phi_k fp32
    float* vbuf = ws + 3 * FSZ;          // v fp32 ; later reused as hid_bf
    ushort* ub  = (ushort*)(ws + 4 * FSZ);
    ushort* fa_bf  = ub;
    ushort* fb_bf  = ub + FSZ;
    ushort* msg_bf = ub + 2 * FSZ;
    ushort* qb_bf  = ub + 3 * FSZ;
    ushort* wb     = ub + 4 * FSZ;
    ushort* wb1    = wb + 16 * 65536;
    ushort* wb2    = wb1 + 4 * 262144;
    ushort* kvt    = wb2 + 4 * 131072;
    float* kvb = (float*)(kvt + 786432);
    float* ksb = kvb + 524288;
    int* cls0 = (int*)(ksb + 16384);
    int* cls1 = cls0 + 38400;
    int* tl0  = cls1 + 38400;
    int* tl1  = tl0 + 38400;
    int* meta = tl1 + 38400;
    ushort* hid_bf = (ushort*)vbuf;

    lft_wconv_kernel<<<dim3(8, 8, 16), 256, 0, stream>>>(Wq, Wk, Wv, Wm, 256, 256, 4, wb);
    lft_wconv_kernel<<<dim3(16, 16, 4), 256, 0, stream>>>(W1, W1, W1, W1, 512, 512, 1, wb1);
    lft_wconv_kernel<<<dim3(16, 8, 4), 256, 0, stream>>>(W2, W2, W2, W2, 512, 256, 1, wb2);
    lft_cast_kernel<<<19200, 256, 0, stream>>>(feat0, feat1, fa_bf, fb_bf);
    hipMemcpyAsync(out + 20352000L, proto, 2048 * 4, hipMemcpyDeviceToDevice, stream);
    lft_class_kernel<<<300, 256, 0, stream>>>(f0wo, f1wo, mask0, mask1, proto,
                                              out, cls0, cls1);
    lft_sort_kernel<<<16, 256, 0, stream>>>(cls0, cls1, tl0, tl1, meta);

    for (int li = 0; li < 4; li++) {
        const ushort* wq = wb + (size_t)(li * 4 + 0) * 65536;   // [wq|wk|wv|wm] contiguous
        const ushort* wk = wb + (size_t)(li * 4 + 1) * 65536;
        const ushort* wm = wb + (size_t)(li * 4 + 3) * 65536;
        const ushort* w1 = wb1 + (size_t)li * 262144;
        const ushort* w2 = wb2 + (size_t)li * 131072;
        const float* g1p = g1 + li * 256; const float* b1p = b1 + li * 256;
        const float* g2p = g2 + li * 256; const float* b2p = b2 + li * 256;

        auto call = [&](ushort* x_bf, ushort* s_bf, const int* clsx,
                        const int* tlx, const int* mtx,
                        const int* tls, const int* mts,
                        const float* residp, float* outFp, bool selfself) {
            dim3 blk(256);
            if (selfself) {
                // q|k|v fused: one pass over x_bf, N=768 ([wq|wk|wv] contiguous)
                lft_mfma_gemm<<<dim3(6, 300), blk, 0, stream>>>(
                    x_bf, x_bf, 256, wq, kbuf, qb_bf, vbuf, 768, 256, 3);
            } else {
                lft_mfma_gemm<<<dim3(2, 300), blk, 0, stream>>>(
                    x_bf, x_bf, 256, wq, nullptr, qb_bf, nullptr, 256, 256, 1);
                // k|v fused over s_bf, N=512 ([wk|wv] contiguous)
                lft_mfma_gemm<<<dim3(4, 300), blk, 0, stream>>>(
                    s_bf, s_bf, 256, wk, kbuf, nullptr, vbuf, 512, 256, 4);
            }
            hipMemsetAsync(kvb, 0, (524288 + 16384) * 4, stream);
            lft_kv_kernel<<<dim3(KV_NCH, 8, 64), 256, 0, stream>>>(kbuf, vbuf, tls, mts, kvb, ksb);
            lft_kvconv_kernel<<<64, 256, 0, stream>>>(kvb, ksb, kvt);
            lft_msg_kernel<<<dim3(MSG_NCH, 8, 8), 256, 0, stream>>>(qb_bf, kvt, tlx, mtx, msg_bf);
            // msg = LN(msg @ Wm)*g1+b1   (fused GEMM+LN, in-place bf16 out)
            lft_gemm_ln<<<600, blk, 0, stream>>>(msg_bf, msg_bf, 256, wm, 256,
                                                 g1p, b1p, nullptr, nullptr, nullptr, msg_bf);
            // hid = relu([x|msg]@W1)
            lft_mfma_gemm<<<dim3(4, 300), blk, 0, stream>>>(
                x_bf, msg_bf, 256, w1, nullptr, hid_bf, nullptr, 512, 512, 2);
            // out = valid ? resid + LN(hid@W2) : resid   (fused GEMM+LN)
            lft_gemm_ln<<<600, blk, 0, stream>>>(hid_bf, hid_bf, 512, w2, 512,
                                                 g2p, b2p, residp, clsx, outFp, x_bf);
        };

        const float* ra = (li == 0) ? feat0 : fa;
        const float* rb = (li == 0) ? feat1 : fb;
        float* oa = (li == 3) ? out : fa;
        float* ob = (li == 3) ? (out + FSZ) : fb;

        if ((li & 1) == 0) {           // self-self
            call(fa_bf, fa_bf, cls0, tl0, meta,       tl0, meta,       ra, oa, true);
            call(fb_bf, fb_bf, cls1, tl1, meta + 128, tl1, meta + 128, rb, ob, true);
        } else {                       // cross-self
            call(fa_bf, fb_bf, cls0, tl0, meta,       tl1, meta + 128, ra, oa, false);
            call(fb_bf, fa_bf, cls1, tl1, meta + 128, tl0, meta,       rb, ob, false);
        }
    }
}

// Round 8
// 2238.935 us; speedup vs baseline: 1.2425x; 1.2425x over previous
//
#include <hip/hip_runtime.h>
#include <math.h>

#define NPROTO 8
#define KV_NCH 4
#define MSG_NCH 8

typedef __attribute__((ext_vector_type(8))) short short8;
typedef __attribute__((ext_vector_type(4))) float floatx4;

static __device__ __forceinline__ ushort f2b(float f) {
    unsigned u = __builtin_bit_cast(unsigned, f);
    unsigned r = (u + 0x7fffu + ((u >> 16) & 1u)) >> 16;
    return (ushort)r;
}

static __device__ __forceinline__ float elu1(float v) {
    return v > 0.f ? v + 1.f : __expf(v);
}

// async 16B global -> LDS (linear dest: wave base + lane*16B)
#define GLOAD16(gp, lp) __builtin_amdgcn_global_load_lds( \
    (const __attribute__((address_space(1))) void*)(gp),  \
    (__attribute__((address_space(3))) void*)(lp), 16, 0, 0)

// drain staging loads + retire LDS reads, then raw barrier (memory-fenced)
#define WAIT_BAR() asm volatile("s_waitcnt vmcnt(0) lgkmcnt(0)\n\ts_barrier" ::: "memory")

// swizzle of the 16B-group index within a 32-col bf16 row (4 groups/row):
// lds[r][cg] holds global[r][cg ^ g(r)], g(r) = (r>>1)&3 -> 2-way (free) banks
static __device__ __forceinline__ int swz(int r) { return (r >> 1) & 3; }

// ---------------- prototype projection / argmax-class kernel ----------------
__global__ __launch_bounds__(256) void lft_class_kernel(
    const float* __restrict__ f0wo, const float* __restrict__ f1wo,
    const int* __restrict__ mask0, const int* __restrict__ mask1,
    const float* __restrict__ proto,
    float* out, int* cls0, int* cls1)
{
    __shared__ float pr[2048];          // proto [8][256]
    __shared__ float tile[256][64];     // [token][ch], swizzled in ch
    int t = threadIdx.x;
    *(float4*)&pr[t * 4]        = *(const float4*)&proto[t * 4];
    *(float4*)&pr[1024 + t * 4] = *(const float4*)&proto[1024 + t * 4];
    long tok0 = (long)blockIdx.x * 256;
    const float* fsrc; const int* msrc; float* fpout; float* clsout; int* clsarr; long tbase;
    if (tok0 < 38400) {
        tbase = tok0; fsrc = f0wo; msrc = mask0;
        fpout = out + 19737600L; clsout = out + 19660800L; clsarr = cls0;
    } else {
        tbase = tok0 - 38400; fsrc = f1wo; msrc = mask1;
        fpout = out + 20044800L; clsout = out + 19699200L; clsarr = cls1;
    }
    float s[NPROTO] = {};
    int r0 = t >> 4;            // 0..15
    int c4 = (t & 15) << 2;     // 0..60
    for (int ct = 0; ct < 4; ct++) {
        __syncthreads();
#pragma unroll
        for (int rr = 0; rr < 16; rr++) {
            int row = rr * 16 + r0;
            float4 v = *(const float4*)&fsrc[(tbase + row) * 256 + ct * 64 + c4];
            *(float4*)&tile[row][c4 ^ ((row & 7) << 2)] = v;
        }
        __syncthreads();
#pragma unroll
        for (int cc = 0; cc < 16; cc++) {
            float4 f = *(const float4*)&tile[t][(cc << 2) ^ ((t & 7) << 2)];
#pragma unroll
            for (int p = 0; p < NPROTO; p++) {
                float4 pv = *(const float4*)&pr[p * 256 + ct * 64 + (cc << 2)];
                s[p] += f.x * pv.x + f.y * pv.y + f.z * pv.z + f.w * pv.w;
            }
        }
    }
    long tok = tbase + t;
    int best = 0; float bv = s[0];
#pragma unroll
    for (int p = 1; p < NPROTO; p++) { if (s[p] > bv) { bv = s[p]; best = p; } }
#pragma unroll
    for (int p = 0; p < NPROTO; p++) fpout[tok * 8 + p] = s[p];
    clsout[tok] = (float)best;
    clsarr[tok] = msrc[tok] ? best : -1;
}

// ---------------- counting sort of tokens by (batch,class) -------------------
__global__ __launch_bounds__(256) void lft_sort_kernel(
    const int* __restrict__ cls0, const int* __restrict__ cls1,
    int* tl0, int* tl1, int* meta)
{
    int g = blockIdx.x; int L = g >> 3, b = g & 7;
    const int* cls = (L ? cls1 : cls0) + b * 4800;
    int* tl = (L ? tl1 : tl0) + b * 4800;
    int* mt = meta + (L * 8 + b) * 16;
    __shared__ int cnt[8], base[8], pos[8];
    int t = threadIdx.x;
    if (t < 8) cnt[t] = 0;
    __syncthreads();
    for (int tok = t; tok < 4800; tok += 256) {
        int c = cls[tok];
        if (c >= 0) atomicAdd(&cnt[c], 1);
    }
    __syncthreads();
    if (t == 0) {
        int s = 0;
        for (int c = 0; c < 8; c++) { base[c] = s; pos[c] = s; s += cnt[c]; }
    }
    __syncthreads();
    if (t < 8) { mt[t * 2] = base[t]; mt[t * 2 + 1] = cnt[t]; }
    for (int tok = t; tok < 4800; tok += 256) {
        int c = cls[tok];
        if (c >= 0) { int p = atomicAdd(&pos[c], 1); tl[p] = tok; }
    }
}

// ---------------- weight convert + transpose: Wt[n*K+k] = bf16(W[k*N+n]) ----
__global__ __launch_bounds__(256) void lft_wconv_kernel(
    const float* W0, const float* W1p, const float* W2p, const float* W3p,
    int K, int N, int nTypes, ushort* dst)
{
    int z = blockIdx.z;
    int li = z / nTypes, mi = z % nTypes;
    const float* srcs[4] = {W0, W1p, W2p, W3p};
    const float* src = srcs[mi] + (size_t)li * K * N;
    ushort* outp = dst + (size_t)z * K * N;
    __shared__ float tile[32][33];
    int k0 = blockIdx.x * 32, n0 = blockIdx.y * 32;
    int t = threadIdx.x;
    int r = t >> 3, c4 = (t & 7) << 2;
    float4 v = *(const float4*)&src[(size_t)(k0 + r) * N + n0 + c4];
    tile[r][c4] = v.x; tile[r][c4 + 1] = v.y; tile[r][c4 + 2] = v.z; tile[r][c4 + 3] = v.w;
    __syncthreads();
    ushort4 o;
    o.x = f2b(tile[c4 + 0][r]);
    o.y = f2b(tile[c4 + 1][r]);
    o.z = f2b(tile[c4 + 2][r]);
    o.w = f2b(tile[c4 + 3][r]);
    *(ushort4*)&outp[(size_t)(n0 + r) * K + k0 + c4] = o;
}

// ---------------- bf16 cast of feat0/feat1 (shadows only) ----------------
__global__ __launch_bounds__(256) void lft_cast_kernel(
    const float* __restrict__ f0, const float* __restrict__ f1,
    ushort* fab, ushort* fbb)
{
    long idx = ((long)blockIdx.x * 256 + threadIdx.x) * 4;
    const float* src; ushort* db; long o;
    if (idx < 9830400L) { src = f0; db = fab; o = idx; }
    else                { src = f1; db = fbb; o = idx - 9830400L; }
    float4 v = *(const float4*)&src[o];
    ushort4 u; u.x = f2b(v.x); u.y = f2b(v.y); u.z = f2b(v.z); u.w = f2b(v.w);
    *(ushort4*)&db[o] = u;
}

// ---------------- bf16 MFMA GEMM: C[38400,N] = act([A0|A1] @ Wt^T) ----------
// Counted 2-phase pipeline: global_load_lds (16B) into linear swizzled LDS,
// double-buffered; one vmcnt/lgkm drain + raw barrier per K-step.
// act: 0 none, 1 elu+1, 2 relu  -> Cf (fp32, stride N) / Cb (bf16, stride N)
// act 3: qkv-fused N=768: col<256 -> Cb=q bf16 elu ; <512 -> Cf=phi_k fp32 ;
//        else Cv=v fp32.   act 4: kv-fused N=512: Cf=phi_k ; Cv=v.
__global__ __launch_bounds__(256) void lft_mfma_gemm(
    const ushort* __restrict__ A0, const ushort* __restrict__ A1, int kSplit,
    const ushort* __restrict__ Wt,
    float* Cf, ushort* Cb, float* Cv, int N, int K, int act)
{
    __shared__ ushort As[2][128 * 32];
    __shared__ ushort Bs[2][128 * 32];
    int t = threadIdx.x;
    int m0 = blockIdx.y << 7;
    int n0 = blockIdx.x << 7;
    int wv = t >> 6, lane = t & 63;
    int wm = wv >> 1, wn = wv & 1;
    int l16 = lane & 15, quad = lane >> 4;
    floatx4 acc[4][4] = {};

    int lrow = lane >> 2;          // 0..15 row-within-group
    int lcg = lane & 3;            // 16B group 0..3

    auto stage = [&](int buf, int k0) {
        const ushort* Asrc; int kcol, ldA;
        if (k0 < kSplit) { Asrc = A0; kcol = k0;          ldA = kSplit; }
        else             { Asrc = A1; kcol = k0 - kSplit; ldA = K - kSplit; }
        ushort* Ab = &As[buf][0];
        ushort* Bb = &Bs[buf][0];
#pragma unroll
        for (int s = 0; s < 2; s++) {
            int r = s * 64 + wv * 16 + lrow;
            int cgA = (lcg ^ swz(r)) << 3;
            GLOAD16(&Asrc[(size_t)(m0 + r) * ldA + kcol + cgA], &Ab[(s * 64 + wv * 16) * 32]);
            GLOAD16(&Wt[(size_t)(n0 + r) * K + k0 + cgA], &Bb[(s * 64 + wv * 16) * 32]);
        }
    };

    int nt = K >> 5;
    stage(0, 0);
    WAIT_BAR();
    int cur = 0;
    for (int tt = 0; tt < nt; ++tt) {
        if (tt + 1 < nt) stage(cur ^ 1, (tt + 1) << 5);
        const ushort* Ab = &As[cur][0];
        const ushort* Bb = &Bs[cur][0];
        short8 af[4], bfr[4];
#pragma unroll
        for (int i = 0; i < 4; i++) {
            int rA = wm * 64 + i * 16 + l16;
            int rB = wn * 64 + i * 16 + l16;
            af[i]  = *(const short8*)&Ab[rA * 32 + ((quad ^ swz(rA)) << 3)];
            bfr[i] = *(const short8*)&Bb[rB * 32 + ((quad ^ swz(rB)) << 3)];
        }
#pragma unroll
        for (int i = 0; i < 4; i++)
#pragma unroll
            for (int j = 0; j < 4; j++)
                acc[i][j] = __builtin_amdgcn_mfma_f32_16x16x32_bf16(af[i], bfr[j], acc[i][j], 0, 0, 0);
        if (tt + 1 < nt) { WAIT_BAR(); cur ^= 1; }
    }
#pragma unroll
    for (int i = 0; i < 4; i++) {
#pragma unroll
        for (int j = 0; j < 4; j++) {
#pragma unroll
            for (int r = 0; r < 4; r++) {
                float v = acc[i][j][r];
                long row = m0 + wm * 64 + i * 16 + quad * 4 + r;
                int col = n0 + wn * 64 + j * 16 + l16;
                if (act == 3) {
                    if (col < 256)      Cb[row * 256 + col] = f2b(elu1(v));
                    else if (col < 512) Cf[row * 256 + col - 256] = elu1(v);
                    else                Cv[row * 256 + col - 512] = v;
                } else if (act == 4) {
                    if (col < 256) Cf[row * 256 + col] = elu1(v);
                    else           Cv[row * 256 + col - 256] = v;
                } else {
                    if (act == 1)      v = elu1(v);
                    else if (act == 2) v = fmaxf(v, 0.f);
                    if (Cf) Cf[row * N + col] = v;
                    if (Cb) Cb[row * N + col] = f2b(v);
                }
            }
        }
    }
}

// ---------------- fused GEMM (N=256) + row-LayerNorm epilogue ----------------
// M=32 tile (grid 1200 -> 4 blocks/CU, fixes the grid-capped 20% occupancy of
// the M=64 version). Wave w owns cols [64w,64w+64); same 2-phase drain
// pipeline and swizzled LDS as lft_mfma_gemm.
__global__ __launch_bounds__(256) void lft_gemm_ln(
    const ushort* __restrict__ A0, const ushort* __restrict__ A1, int kSplit,
    const ushort* __restrict__ Wt, int K,
    const float* __restrict__ g, const float* __restrict__ bb,
    const float* __restrict__ resid, const int* __restrict__ cls,
    float* outF, ushort* __restrict__ outB)
{
    __shared__ ushort As[2][32 * 32];
    __shared__ ushort Bs[2][256 * 32];
    __shared__ float gs[256], bs[256];
    __shared__ float psum[4][32], psq[4][32];
    int t = threadIdx.x;
    long m0 = (long)blockIdx.x << 5;
    int wv = t >> 6, lane = t & 63;
    int l16 = lane & 15, quad = lane >> 4;
    gs[t] = g[t]; bs[t] = bb[t];
    floatx4 acc[2][4] = {};

    int lrow = lane >> 2;
    int lcg = lane & 3;

    auto stage = [&](int buf, int k0) {
        const ushort* Asrc; int kcol, ldA;
        if (k0 < kSplit) { Asrc = A0; kcol = k0;          ldA = kSplit; }
        else             { Asrc = A1; kcol = k0 - kSplit; ldA = K - kSplit; }
        if (wv < 2) {                                        // A rows 0..31
            int r = wv * 16 + lrow;
            int cgA = (lcg ^ swz(r)) << 3;
            GLOAD16(&Asrc[(m0 + r) * ldA + kcol + cgA], &As[buf][(wv * 16) * 32]);
        }
#pragma unroll
        for (int s = 0; s < 4; s++) {                        // B rows 0..255
            int r = s * 64 + wv * 16 + lrow;
            int cgB = (lcg ^ swz(r)) << 3;
            GLOAD16(&Wt[(size_t)r * K + k0 + cgB], &Bs[buf][(s * 64 + wv * 16) * 32]);
        }
    };

    int nt = K >> 5;
    stage(0, 0);
    WAIT_BAR();
    int cur = 0;
    for (int tt = 0; tt < nt; ++tt) {
        if (tt + 1 < nt) stage(cur ^ 1, (tt + 1) << 5);
        const ushort* Ab = &As[cur][0];
        const ushort* Bb = &Bs[cur][0];
        short8 af[2], bfr[4];
#pragma unroll
        for (int i = 0; i < 2; i++) {
            int rA = i * 16 + l16;
            af[i] = *(const short8*)&Ab[rA * 32 + ((quad ^ swz(rA)) << 3)];
        }
#pragma unroll
        for (int j = 0; j < 4; j++) {
            int rB = wv * 64 + j * 16 + l16;
            bfr[j] = *(const short8*)&Bb[rB * 32 + ((quad ^ swz(rB)) << 3)];
        }
#pragma unroll
        for (int i = 0; i < 2; i++)
#pragma unroll
            for (int j = 0; j < 4; j++)
                acc[i][j] = __builtin_amdgcn_mfma_f32_16x16x32_bf16(af[i], bfr[j], acc[i][j], 0, 0, 0);
        if (tt + 1 < nt) { WAIT_BAR(); cur ^= 1; }
    }
    // per-row partial sums (this wave's 64 cols) -> LDS
#pragma unroll
    for (int i = 0; i < 2; i++) {
#pragma unroll
        for (int r = 0; r < 4; r++) {
            float s = 0.f, q = 0.f;
#pragma unroll
            for (int j = 0; j < 4; j++) { float v = acc[i][j][r]; s += v; q += v * v; }
#pragma unroll
            for (int o = 8; o >= 1; o >>= 1) {
                s += __shfl_xor(s, o, 64);
                q += __shfl_xor(q, o, 64);
            }
            if (l16 == 0) {
                int row = i * 16 + quad * 4 + r;
                psum[wv][row] = s; psq[wv][row] = q;
            }
        }
    }
    __syncthreads();
    if (t < 32) {
        float s = psum[0][t] + psum[1][t] + psum[2][t] + psum[3][t];
        float q = psq[0][t] + psq[1][t] + psq[2][t] + psq[3][t];
        float mean = s * (1.0f / 256.0f);
        float var = q * (1.0f / 256.0f) - mean * mean;
        psum[0][t] = mean;
        psq[0][t] = rsqrtf(var + 1e-5f);
    }
    __syncthreads();
#pragma unroll
    for (int i = 0; i < 2; i++) {
#pragma unroll
        for (int r = 0; r < 4; r++) {
            int rloc = i * 16 + quad * 4 + r;
            long grow = m0 + rloc;
            float mean = psum[0][rloc], rstd = psq[0][rloc];
            int cv = cls ? cls[grow] : 0;
#pragma unroll
            for (int j = 0; j < 4; j++) {
                int col = wv * 64 + j * 16 + l16;
                float y = (acc[i][j][r] - mean) * rstd * gs[col] + bs[col];
                if (resid) {
                    float xr = resid[grow * 256 + col];
                    y = (cv >= 0) ? xr + y : xr;
                }
                if (outF) outF[grow * 256 + col] = y;
                outB[grow * 256 + col] = f2b(y);
            }
        }
    }
}

// ---------------- per-class KV / Ksum reduction (SRC-side token lists) --------
__global__ __launch_bounds__(256) void lft_kv_kernel(
    const float* __restrict__ phik, const float* __restrict__ vmat,
    const int* __restrict__ tlist, const int* __restrict__ meta,
    float* kv, float* ksum)
{
    int chunk = blockIdx.x, c = blockIdx.y;
    int b = blockIdx.z >> 3, h = blockIdx.z & 7;
    int off = meta[(b * 8 + c) * 2], n = meta[(b * 8 + c) * 2 + 1];
    int per = (n + KV_NCH - 1) / KV_NCH;
    int s0 = chunk * per;
    int s1 = min(s0 + per, n);
    if (s0 >= s1) return;
    const int* tl = tlist + b * 4800 + off;
    int t = threadIdx.x;
    __shared__ float kb[8][32];
    __shared__ float vb[8][32];
    int od = t >> 3, oe = (t & 7) << 2;
    int lt = t >> 5, ld = t & 31;
    float a0 = 0.f, a1 = 0.f, a2 = 0.f, a3 = 0.f, ak = 0.f;
    for (int s = s0; s < s1; s += 8) {
        float kval = 0.f, vval = 0.f;
        if (s + lt < s1) {
            int tok = tl[s + lt];
            long bse = ((long)b * 4800 + tok) * 256 + h * 32 + ld;
            kval = phik[bse];
            vval = vmat[bse];
        }
        __syncthreads();
        kb[lt][ld] = kval;
        vb[lt][ld] = vval;
        __syncthreads();
#pragma unroll
        for (int j = 0; j < 8; j++) {
            float kd = kb[j][od];
            float4 vv = *(const float4*)&vb[j][oe];
            a0 += kd * vv.x; a1 += kd * vv.y; a2 += kd * vv.z; a3 += kd * vv.w;
            ak += kd;
        }
    }
    float* dst = kv + (((long)(b * NPROTO + c) * 8 + h) << 10) + od * 32 + oe;
    atomicAdd(dst + 0, a0);
    atomicAdd(dst + 1, a1);
    atomicAdd(dst + 2, a2);
    atomicAdd(dst + 3, a3);
    if ((t & 7) == 0)
        atomicAdd(ksum + (((long)(b * NPROTO + c) * 8 + h) << 5) + od, ak);
}

// ---------------- kv fp32 [d][e] + ksum → bf16 B-layout [e'][d], e'<48 -------
__global__ __launch_bounds__(256) void lft_kvconv_kernel(
    const float* __restrict__ kvb, const float* __restrict__ ksb,
    ushort* __restrict__ kvt)
{
    int bc = blockIdx.x;          // b*8+c
    int t = threadIdx.x;
    int h = t >> 5, d = t & 31;
    const float* kvsrc = kvb + ((long)bc * 8 + h) * 1024;
    const float* kssrc = ksb + ((long)bc * 8 + h) * 32;
    ushort* dst = kvt + ((long)bc * 8 + h) * 1536;
#pragma unroll
    for (int e = 0; e < 32; e++) dst[e * 32 + d] = f2b(kvsrc[d * 32 + e]);
    dst[32 * 32 + d] = f2b(kssrc[d]);
#pragma unroll
    for (int e = 33; e < 48; e++) dst[e * 32 + d] = 0;
}

// ---------------- msg via MFMA over X-SIDE class-sorted lists ----------------
__global__ __launch_bounds__(256) void lft_msg_kernel(
    const ushort* __restrict__ pq, const ushort* __restrict__ kvt,
    const int* __restrict__ tlist, const int* __restrict__ meta,
    ushort* __restrict__ msg)
{
    int chunk = blockIdx.x, c = blockIdx.y, b = blockIdx.z;
    int off = meta[(b * 8 + c) * 2], n = meta[(b * 8 + c) * 2 + 1];
    int per = (n + MSG_NCH - 1) / MSG_NCH;
    int s0 = chunk * per, s1 = min(s0 + per, n);
    if (s0 >= s1) return;
    const int* tl = tlist + b * 4800 + off;
    int t = threadIdx.x;
    int wave = t >> 6, lane = t & 63;
    int l16 = lane & 15, quad = lane >> 4;
    int bc = b * 8 + c;
    short8 bfr[2][3];
#pragma unroll
    for (int hh = 0; hh < 2; hh++) {
        int h = wave * 2 + hh;
        const ushort* kb = kvt + ((long)bc * 8 + h) * 1536;
#pragma unroll
        for (int nt = 0; nt < 3; nt++)
            bfr[hh][nt] = *(const short8*)&kb[(nt * 16 + l16) * 32 + quad * 8];
    }
    for (int s = s0; s < s1; s += 16) {
        int ia = min(s + l16, s1 - 1);
        int tokA = tl[ia];
        long rowA = (long)b * 4800 + tokA;
#pragma unroll
        for (int hh = 0; hh < 2; hh++) {
            int h = wave * 2 + hh;
            short8 a = *(const short8*)&pq[rowA * 256 + h * 32 + quad * 8];
            floatx4 n0 = {}, n1 = {}, dd = {};
            n0 = __builtin_amdgcn_mfma_f32_16x16x32_bf16(a, bfr[hh][0], n0, 0, 0, 0);
            n1 = __builtin_amdgcn_mfma_f32_16x16x32_bf16(a, bfr[hh][1], n1, 0, 0, 0);
            dd = __builtin_amdgcn_mfma_f32_16x16x32_bf16(a, bfr[hh][2], dd, 0, 0, 0);
#pragma unroll
            for (int r = 0; r < 4; r++) {
                int rowi = s + quad * 4 + r;
                float den = __shfl(dd[r], lane & 48, 64);
                float inv = 1.f / (den + 1e-6f);
                int tokr = __shfl(tokA, quad * 4 + r, 64);
                if (rowi < s1) {
                    long base = ((long)b * 4800 + tokr) * 256 + h * 32;
                    msg[base + l16]      = f2b(n0[r] * inv);
                    msg[base + 16 + l16] = f2b(n1[r] * inv);
                }
            }
        }
    }
}

extern "C" void kernel_launch(void* const* d_in, const int* in_sizes, int n_in,
                              void* d_out, int out_size, void* d_ws, size_t ws_size,
                              hipStream_t stream)
{
    (void)in_sizes; (void)n_in; (void)out_size; (void)ws_size;
    const float* feat0 = (const float*)d_in[0];
    const float* feat1 = (const float*)d_in[1];
    const int*   mask0 = (const int*)d_in[2];
    const int*   mask1 = (const int*)d_in[3];
    const float* f0wo  = (const float*)d_in[4];
    const float* f1wo  = (const float*)d_in[5];
    const float* proto = (const float*)d_in[6];
    const float* Wq = (const float*)d_in[7];
    const float* Wk = (const float*)d_in[8];
    const float* Wv = (const float*)d_in[9];
    const float* Wm = (const float*)d_in[10];
    const float* W1 = (const float*)d_in[11];
    const float* W2 = (const float*)d_in[12];
    const float* g1 = (const float*)d_in[13];
    const float* b1 = (const float*)d_in[14];
    const float* g2 = (const float*)d_in[15];
    const float* b2 = (const float*)d_in[16];
    float* out = (float*)d_out;
    float* ws = (float*)d_ws;

    // ---- workspace layout (unchanged) ----
    const long FSZ = 9830400L;           // 8*4800*256
    float* fa   = ws;
    float* fb   = ws + FSZ;
    float* kbuf = ws + 2 * FSZ;          // phi_k fp32
    float* vbuf = ws + 3 * FSZ;          // v fp32 ; later reused as hid_bf
    ushort* ub  = (ushort*)(ws + 4 * FSZ);
    ushort* fa_bf  = ub;
    ushort* fb_bf  = ub + FSZ;
    ushort* msg_bf = ub + 2 * FSZ;
    ushort* qb_bf  = ub + 3 * FSZ;
    ushort* wb     = ub + 4 * FSZ;
    ushort* wb1    = wb + 16 * 65536;
    ushort* wb2    = wb1 + 4 * 262144;
    ushort* kvt    = wb2 + 4 * 131072;
    float* kvb = (float*)(kvt + 786432);
    float* ksb = kvb + 524288;
    int* cls0 = (int*)(ksb + 16384);
    int* cls1 = cls0 + 38400;
    int* tl0  = cls1 + 38400;
    int* tl1  = tl0 + 38400;
    int* meta = tl1 + 38400;
    ushort* hid_bf = (ushort*)vbuf;

    lft_wconv_kernel<<<dim3(8, 8, 16), 256, 0, stream>>>(Wq, Wk, Wv, Wm, 256, 256, 4, wb);
    lft_wconv_kernel<<<dim3(16, 16, 4), 256, 0, stream>>>(W1, W1, W1, W1, 512, 512, 1, wb1);
    lft_wconv_kernel<<<dim3(16, 8, 4), 256, 0, stream>>>(W2, W2, W2, W2, 512, 256, 1, wb2);
    lft_cast_kernel<<<19200, 256, 0, stream>>>(feat0, feat1, fa_bf, fb_bf);
    hipMemcpyAsync(out + 20352000L, proto, 2048 * 4, hipMemcpyDeviceToDevice, stream);
    lft_class_kernel<<<300, 256, 0, stream>>>(f0wo, f1wo, mask0, mask1, proto,
                                              out, cls0, cls1);
    lft_sort_kernel<<<16, 256, 0, stream>>>(cls0, cls1, tl0, tl1, meta);

    for (int li = 0; li < 4; li++) {
        const ushort* wq = wb + (size_t)(li * 4 + 0) * 65536;   // [wq|wk|wv|wm] contiguous
        const ushort* wk = wb + (size_t)(li * 4 + 1) * 65536;
        const ushort* wm = wb + (size_t)(li * 4 + 3) * 65536;
        const ushort* w1 = wb1 + (size_t)li * 262144;
        const ushort* w2 = wb2 + (size_t)li * 131072;
        const float* g1p = g1 + li * 256; const float* b1p = b1 + li * 256;
        const float* g2p = g2 + li * 256; const float* b2p = b2 + li * 256;

        auto call = [&](ushort* x_bf, ushort* s_bf, const int* clsx,
                        const int* tlx, const int* mtx,
                        const int* tls, const int* mts,
                        const float* residp, float* outFp, bool selfself) {
            dim3 blk(256);
            if (selfself) {
                // q|k|v fused: one pass over x_bf, N=768 ([wq|wk|wv] contiguous)
                lft_mfma_gemm<<<dim3(6, 300), blk, 0, stream>>>(
                    x_bf, x_bf, 256, wq, kbuf, qb_bf, vbuf, 768, 256, 3);
            } else {
                lft_mfma_gemm<<<dim3(2, 300), blk, 0, stream>>>(
                    x_bf, x_bf, 256, wq, nullptr, qb_bf, nullptr, 256, 256, 1);
                // k|v fused over s_bf, N=512 ([wk|wv] contiguous)
                lft_mfma_gemm<<<dim3(4, 300), blk, 0, stream>>>(
                    s_bf, s_bf, 256, wk, kbuf, nullptr, vbuf, 512, 256, 4);
            }
            hipMemsetAsync(kvb, 0, (524288 + 16384) * 4, stream);
            lft_kv_kernel<<<dim3(KV_NCH, 8, 64), blk, 0, stream>>>(kbuf, vbuf, tls, mts, kvb, ksb);
            lft_kvconv_kernel<<<64, blk, 0, stream>>>(kvb, ksb, kvt);
            lft_msg_kernel<<<dim3(MSG_NCH, 8, 8), blk, 0, stream>>>(qb_bf, kvt, tlx, mtx, msg_bf);
            // msg = LN(msg @ Wm)*g1+b1   (fused GEMM+LN, in-place bf16 out)
            lft_gemm_ln<<<1200, blk, 0, stream>>>(msg_bf, msg_bf, 256, wm, 256,
                                                  g1p, b1p, nullptr, nullptr, nullptr, msg_bf);
            // hid = relu([x|msg]@W1)
            lft_mfma_gemm<<<dim3(4, 300), blk, 0, stream>>>(
                x_bf, msg_bf, 256, w1, nullptr, hid_bf, nullptr, 512, 512, 2);
            // out = valid ? resid + LN(hid@W2) : resid   (fused GEMM+LN)
            lft_gemm_ln<<<1200, blk, 0, stream>>>(hid_bf, hid_bf, 512, w2, 512,
                                                  g2p, b2p, residp, clsx, outFp, x_bf);
        };

        const float* ra = (li == 0) ? feat0 : fa;
        const float* rb = (li == 0) ? feat1 : fb;
        float* oa = (li == 3) ? out : fa;
        float* ob = (li == 3) ? (out + FSZ) : fb;

        if ((li & 1) == 0) {           // self-self
            call(fa_bf, fa_bf, cls0, tl0, meta,       tl0, meta,       ra, oa, true);
            call(fb_bf, fb_bf, cls1, tl1, meta + 128, tl1, meta + 128, rb, ob, true);
        } else {                       // cross-self
            call(fa_bf, fb_bf, cls0, tl0, meta,       tl1, meta + 128, ra, oa, false);
            call(fb_bf, fa_bf, cls1, tl1, meta + 128, tl0, meta,       rb, ob, false);
        }
    }
}

// Round 9
// 1583.378 us; speedup vs baseline: 1.7570x; 1.4140x over previous
//
#include <hip/hip_runtime.h>
#include <math.h>

#define NPROTO 8
#define KV_NCH 4
#define MSG_NCH 8

typedef __attribute__((ext_vector_type(8))) short short8;
typedef __attribute__((ext_vector_type(4))) float floatx4;

static __device__ __forceinline__ ushort f2b(float f) {
    unsigned u = __builtin_bit_cast(unsigned, f);
    unsigned r = (u + 0x7fffu + ((u >> 16) & 1u)) >> 16;
    return (ushort)r;
}

static __device__ __forceinline__ float elu1(float v) {
    return v > 0.f ? v + 1.f : __expf(v);
}

// async 16B global -> LDS (linear dest: wave base + lane*16B)
#define GLOAD16(gp, lp) __builtin_amdgcn_global_load_lds( \
    (const __attribute__((address_space(1))) void*)(gp),  \
    (__attribute__((address_space(3))) void*)(lp), 16, 0, 0)

// drain staging loads + retire LDS reads, then raw barrier (memory-fenced)
#define WAIT_BAR() asm volatile("s_waitcnt vmcnt(0) lgkmcnt(0)\n\ts_barrier" ::: "memory")

// swizzle of the 16B-group index within a 32-col bf16 row (4 groups/row)
static __device__ __forceinline__ int swz(int r) { return (r >> 1) & 3; }

// ---------------- prototype projection / argmax-class kernel ----------------
__global__ __launch_bounds__(256) void lft_class_kernel(
    const float* __restrict__ f0wo, const float* __restrict__ f1wo,
    const int* __restrict__ mask0, const int* __restrict__ mask1,
    const float* __restrict__ proto,
    float* out, int* cls0, int* cls1)
{
    __shared__ float pr[2048];          // proto [8][256]
    __shared__ float tile[256][64];     // [token][ch], swizzled in ch
    int t = threadIdx.x;
    *(float4*)&pr[t * 4]        = *(const float4*)&proto[t * 4];
    *(float4*)&pr[1024 + t * 4] = *(const float4*)&proto[1024 + t * 4];
    long tok0 = (long)blockIdx.x * 256;
    const float* fsrc; const int* msrc; float* fpout; float* clsout; int* clsarr; long tbase;
    if (tok0 < 38400) {
        tbase = tok0; fsrc = f0wo; msrc = mask0;
        fpout = out + 19737600L; clsout = out + 19660800L; clsarr = cls0;
    } else {
        tbase = tok0 - 38400; fsrc = f1wo; msrc = mask1;
        fpout = out + 20044800L; clsout = out + 19699200L; clsarr = cls1;
    }
    float s[NPROTO] = {};
    int r0 = t >> 4;
    int c4 = (t & 15) << 2;
    for (int ct = 0; ct < 4; ct++) {
        __syncthreads();
#pragma unroll
        for (int rr = 0; rr < 16; rr++) {
            int row = rr * 16 + r0;
            float4 v = *(const float4*)&fsrc[(tbase + row) * 256 + ct * 64 + c4];
            *(float4*)&tile[row][c4 ^ ((row & 7) << 2)] = v;
        }
        __syncthreads();
#pragma unroll
        for (int cc = 0; cc < 16; cc++) {
            float4 f = *(const float4*)&tile[t][(cc << 2) ^ ((t & 7) << 2)];
#pragma unroll
            for (int p = 0; p < NPROTO; p++) {
                float4 pv = *(const float4*)&pr[p * 256 + ct * 64 + (cc << 2)];
                s[p] += f.x * pv.x + f.y * pv.y + f.z * pv.z + f.w * pv.w;
            }
        }
    }
    long tok = tbase + t;
    int best = 0; float bv = s[0];
#pragma unroll
    for (int p = 1; p < NPROTO; p++) { if (s[p] > bv) { bv = s[p]; best = p; } }
#pragma unroll
    for (int p = 0; p < NPROTO; p++) fpout[tok * 8 + p] = s[p];
    clsout[tok] = (float)best;
    clsarr[tok] = msrc[tok] ? best : -1;
}

// ---------------- per-(L,b) class counts -> meta {base,cnt} ------------------
__global__ __launch_bounds__(256) void lft_count_kernel(
    const int* __restrict__ cls0, const int* __restrict__ cls1, int* meta)
{
    int g = blockIdx.x; int L = g >> 3, b = g & 7;
    const int* cls = (L ? cls1 : cls0) + b * 4800;
    int* mt = meta + (L * 8 + b) * 16;
    __shared__ int cnt[8];
    int t = threadIdx.x;
    if (t < 8) cnt[t] = 0;
    __syncthreads();
    for (int tok = t; tok < 4800; tok += 256) {
        int c = cls[tok];
        if (c >= 0) atomicAdd(&cnt[c], 1);
    }
    __syncthreads();
    if (t == 0) {
        int s = 0;
        for (int c = 0; c < 8; c++) { mt[c * 2] = s; mt[c * 2 + 1] = cnt[c]; s += cnt[c]; }
    }
}

// ---------------- cross-batch scan: minfo (Mv, boff) + compact cmeta ---------
// minfo: [0]=mv0 rnd128, [1]=mv1 rnd128, [2]=mv0, [3]=mv1, [4..11]=boff0, [12..19]=boff1
// cmeta[(L*64+b*8+c)*2] = compact start, +1 = cnt
__global__ __launch_bounds__(256) void lft_scan_kernel(
    const int* __restrict__ meta, int* minfo, int* cmeta)
{
    int t = threadIdx.x;
    __shared__ int nb[16];
    if (t < 16) {
        int s = 0;
        for (int c = 0; c < 8; c++) s += meta[t * 16 + c * 2 + 1];
        nb[t] = s;
    }
    __syncthreads();
    if (t == 0) {
        int off = 0;
        for (int b = 0; b < 8; b++) { minfo[4 + b] = off; off += nb[b]; }
        minfo[2] = off; minfo[0] = (off + 127) & ~127;
        off = 0;
        for (int b = 0; b < 8; b++) { minfo[12 + b] = off; off += nb[8 + b]; }
        minfo[3] = off; minfo[1] = (off + 127) & ~127;
    }
    __syncthreads();
    if (t < 128) {
        int L = t >> 6, b = (t >> 3) & 7, c = t & 7;
        cmeta[t * 2]     = minfo[4 + L * 8 + b] + meta[(L * 8 + b) * 16 + c * 2];
        cmeta[t * 2 + 1] = meta[(L * 8 + b) * 16 + c * 2 + 1];
    }
}

// ---------------- place valid tokens into compact gather lists ---------------
__global__ __launch_bounds__(256) void lft_place_kernel(
    const int* __restrict__ cls0, const int* __restrict__ cls1,
    const int* __restrict__ cmeta, int* gl0, int* gl1)
{
    int g = blockIdx.x; int L = g >> 3, b = g & 7;
    const int* cls = (L ? cls1 : cls0) + b * 4800;
    int* gl = L ? gl1 : gl0;
    __shared__ int pos[8];
    int t = threadIdx.x;
    if (t < 8) pos[t] = cmeta[(L * 64 + b * 8 + t) * 2];
    __syncthreads();
    for (int tok = t; tok < 4800; tok += 256) {
        int c = cls[tok];
        if (c >= 0) { int p = atomicAdd(&pos[c], 1); gl[p] = b * 4800 + tok; }
    }
}

// ---------------- gather-cast: compact bf16 x + compact fp32 resid -----------
__global__ __launch_bounds__(256) void lft_gcast_kernel(
    const float* __restrict__ f0, const float* __restrict__ f1,
    const int* __restrict__ gl0, const int* __restrict__ gl1,
    const int* __restrict__ minfo,
    ushort* xc0, ushort* xc1, float* rc0, float* rc1)
{
    int blk = blockIdx.x;
    int side = blk >= 600 ? 1 : 0;
    int i0 = (blk - side * 600) * 4 + (threadIdx.x >> 6);
    int mv = minfo[2 + side];
    const int* gl = side ? gl1 : gl0;
    const float* f = side ? f1 : f0;
    ushort* xc = side ? xc1 : xc0;
    float* rc = side ? rc1 : rc0;
    int lane = threadIdx.x & 63;
    for (int i = i0; i < mv; i += 2400) {
        long src = (long)gl[i] * 256 + lane * 4;
        float4 v = *(const float4*)&f[src];
        long dst = (long)i * 256 + lane * 4;
        *(float4*)&rc[dst] = v;
        ushort4 u; u.x = f2b(v.x); u.y = f2b(v.y); u.z = f2b(v.z); u.w = f2b(v.w);
        *(ushort4*)&xc[dst] = u;
    }
}

// ---------------- weight convert + transpose: Wt[n*K+k] = bf16(W[k*N+n]) ----
__global__ __launch_bounds__(256) void lft_wconv_kernel(
    const float* W0, const float* W1p, const float* W2p, const float* W3p,
    int K, int N, int nTypes, ushort* dst)
{
    int z = blockIdx.z;
    int li = z / nTypes, mi = z % nTypes;
    const float* srcs[4] = {W0, W1p, W2p, W3p};
    const float* src = srcs[mi] + (size_t)li * K * N;
    ushort* outp = dst + (size_t)z * K * N;
    __shared__ float tile[32][33];
    int k0 = blockIdx.x * 32, n0 = blockIdx.y * 32;
    int t = threadIdx.x;
    int r = t >> 3, c4 = (t & 7) << 2;
    float4 v = *(const float4*)&src[(size_t)(k0 + r) * N + n0 + c4];
    tile[r][c4] = v.x; tile[r][c4 + 1] = v.y; tile[r][c4 + 2] = v.z; tile[r][c4 + 3] = v.w;
    __syncthreads();
    ushort4 o;
    o.x = f2b(tile[c4 + 0][r]);
    o.y = f2b(tile[c4 + 1][r]);
    o.z = f2b(tile[c4 + 2][r]);
    o.w = f2b(tile[c4 + 3][r]);
    *(ushort4*)&outp[(size_t)(n0 + r) * K + k0 + c4] = o;
}

// ---------------- bf16 MFMA GEMM over COMPACT rows ---------------------------
// R2-proven 2-phase drain pipeline, 128x128 tile, 4 waves. Early-exit when
// m0 >= mvp[0] (device-side valid-row count rounded to 128).
// act: 0 none, 1 elu+1, 2 relu; act 3 qkv N=768; act 4 kv N=512.
__global__ __launch_bounds__(256) void lft_mfma_gemm(
    const ushort* __restrict__ A0, const ushort* __restrict__ A1, int kSplit,
    const ushort* __restrict__ Wt,
    float* Cf, ushort* Cb, float* Cv, int N, int K, int act,
    const int* __restrict__ mvp)
{
    __shared__ ushort As[2][128 * 32];
    __shared__ ushort Bs[2][128 * 32];
    int m0 = blockIdx.y << 7;
    if (m0 >= mvp[0]) return;
    int t = threadIdx.x;
    int n0 = blockIdx.x << 7;
    int wv = t >> 6, lane = t & 63;
    int wm = wv >> 1, wn = wv & 1;
    int l16 = lane & 15, quad = lane >> 4;
    floatx4 acc[4][4] = {};

    int lrow = lane >> 2;
    int lcg = lane & 3;

    auto stage = [&](int buf, int k0) {
        const ushort* Asrc; int kcol, ldA;
        if (k0 < kSplit) { Asrc = A0; kcol = k0;          ldA = kSplit; }
        else             { Asrc = A1; kcol = k0 - kSplit; ldA = K - kSplit; }
        ushort* Ab = &As[buf][0];
        ushort* Bb = &Bs[buf][0];
#pragma unroll
        for (int s = 0; s < 2; s++) {
            int r = s * 64 + wv * 16 + lrow;
            int cgA = (lcg ^ swz(r)) << 3;
            GLOAD16(&Asrc[(size_t)(m0 + r) * ldA + kcol + cgA], &Ab[(s * 64 + wv * 16) * 32]);
            GLOAD16(&Wt[(size_t)(n0 + r) * K + k0 + cgA], &Bb[(s * 64 + wv * 16) * 32]);
        }
    };

    int nt = K >> 5;
    stage(0, 0);
    WAIT_BAR();
    int cur = 0;
    for (int tt = 0; tt < nt; ++tt) {
        if (tt + 1 < nt) stage(cur ^ 1, (tt + 1) << 5);
        const ushort* Ab = &As[cur][0];
        const ushort* Bb = &Bs[cur][0];
        short8 af[4], bfr[4];
#pragma unroll
        for (int i = 0; i < 4; i++) {
            int rA = wm * 64 + i * 16 + l16;
            int rB = wn * 64 + i * 16 + l16;
            af[i]  = *(const short8*)&Ab[rA * 32 + ((quad ^ swz(rA)) << 3)];
            bfr[i] = *(const short8*)&Bb[rB * 32 + ((quad ^ swz(rB)) << 3)];
        }
#pragma unroll
        for (int i = 0; i < 4; i++)
#pragma unroll
            for (int j = 0; j < 4; j++)
                acc[i][j] = __builtin_amdgcn_mfma_f32_16x16x32_bf16(af[i], bfr[j], acc[i][j], 0, 0, 0);
        if (tt + 1 < nt) { WAIT_BAR(); cur ^= 1; }
    }
#pragma unroll
    for (int i = 0; i < 4; i++) {
#pragma unroll
        for (int j = 0; j < 4; j++) {
#pragma unroll
            for (int r = 0; r < 4; r++) {
                float v = acc[i][j][r];
                long row = m0 + wm * 64 + i * 16 + quad * 4 + r;
                int col = n0 + wn * 64 + j * 16 + l16;
                if (act == 3) {
                    if (col < 256)      Cb[row * 256 + col] = f2b(elu1(v));
                    else if (col < 512) Cf[row * 256 + col - 256] = elu1(v);
                    else                Cv[row * 256 + col - 512] = v;
                } else if (act == 4) {
                    if (col < 256) Cf[row * 256 + col] = elu1(v);
                    else           Cv[row * 256 + col - 256] = v;
                } else {
                    if (act == 1)      v = elu1(v);
                    else if (act == 2) v = fmaxf(v, 0.f);
                    if (Cf) Cf[row * N + col] = v;
                    if (Cb) Cb[row * N + col] = f2b(v);
                }
            }
        }
    }
}

// ---------------- fused GEMM (N=256) + row-LN over COMPACT rows -------------
// M=32 tile, grid 1200 (early-exit at mvp[0]). All rows valid by construction.
// rcIn: compact residual (read, or null); rcOut: write y (compact, or null);
// glp+outSc: scatter y to full layout (guard grow < mvp[2]); outB: compact bf16.
__global__ __launch_bounds__(256) void lft_gemm_ln(
    const ushort* __restrict__ A0, const ushort* __restrict__ A1, int kSplit,
    const ushort* __restrict__ Wt, int K,
    const float* __restrict__ g, const float* __restrict__ bb,
    const float* __restrict__ rcIn, float* rcOut,
    const int* __restrict__ glp, const int* __restrict__ mvp,
    float* outSc, ushort* outB)
{
    __shared__ ushort As[2][32 * 32];
    __shared__ ushort Bs[2][256 * 32];
    __shared__ float gs[256], bs[256];
    __shared__ float psum[4][32], psq[4][32];
    long m0 = (long)blockIdx.x << 5;
    if (m0 >= mvp[0]) return;
    int t = threadIdx.x;
    int wv = t >> 6, lane = t & 63;
    int l16 = lane & 15, quad = lane >> 4;
    gs[t] = g[t]; bs[t] = bb[t];
    floatx4 acc[2][4] = {};

    int lrow = lane >> 2;
    int lcg = lane & 3;

    auto stage = [&](int buf, int k0) {
        const ushort* Asrc; int kcol, ldA;
        if (k0 < kSplit) { Asrc = A0; kcol = k0;          ldA = kSplit; }
        else             { Asrc = A1; kcol = k0 - kSplit; ldA = K - kSplit; }
        if (wv < 2) {                                        // A rows 0..31
            int r = wv * 16 + lrow;
            int cgA = (lcg ^ swz(r)) << 3;
            GLOAD16(&Asrc[(m0 + r) * ldA + kcol + cgA], &As[buf][(wv * 16) * 32]);
        }
#pragma unroll
        for (int s = 0; s < 4; s++) {                        // B rows 0..255
            int r = s * 64 + wv * 16 + lrow;
            int cgB = (lcg ^ swz(r)) << 3;
            GLOAD16(&Wt[(size_t)r * K + k0 + cgB], &Bs[buf][(s * 64 + wv * 16) * 32]);
        }
    };

    int nt = K >> 5;
    stage(0, 0);
    WAIT_BAR();
    int cur = 0;
    for (int tt = 0; tt < nt; ++tt) {
        if (tt + 1 < nt) stage(cur ^ 1, (tt + 1) << 5);
        const ushort* Ab = &As[cur][0];
        const ushort* Bb = &Bs[cur][0];
        short8 af[2], bfr[4];
#pragma unroll
        for (int i = 0; i < 2; i++) {
            int rA = i * 16 + l16;
            af[i] = *(const short8*)&Ab[rA * 32 + ((quad ^ swz(rA)) << 3)];
        }
#pragma unroll
        for (int j = 0; j < 4; j++) {
            int rB = wv * 64 + j * 16 + l16;
            bfr[j] = *(const short8*)&Bb[rB * 32 + ((quad ^ swz(rB)) << 3)];
        }
#pragma unroll
        for (int i = 0; i < 2; i++)
#pragma unroll
            for (int j = 0; j < 4; j++)
                acc[i][j] = __builtin_amdgcn_mfma_f32_16x16x32_bf16(af[i], bfr[j], acc[i][j], 0, 0, 0);
        if (tt + 1 < nt) { WAIT_BAR(); cur ^= 1; }
    }
    // per-row partial sums (this wave's 64 cols) -> LDS
#pragma unroll
    for (int i = 0; i < 2; i++) {
#pragma unroll
        for (int r = 0; r < 4; r++) {
            float s = 0.f, q = 0.f;
#pragma unroll
            for (int j = 0; j < 4; j++) { float v = acc[i][j][r]; s += v; q += v * v; }
#pragma unroll
            for (int o = 8; o >= 1; o >>= 1) {
                s += __shfl_xor(s, o, 64);
                q += __shfl_xor(q, o, 64);
            }
            if (l16 == 0) {
                int row = i * 16 + quad * 4 + r;
                psum[wv][row] = s; psq[wv][row] = q;
            }
        }
    }
    __syncthreads();
    if (t < 32) {
        float s = psum[0][t] + psum[1][t] + psum[2][t] + psum[3][t];
        float q = psq[0][t] + psq[1][t] + psq[2][t] + psq[3][t];
        float mean = s * (1.0f / 256.0f);
        float var = q * (1.0f / 256.0f) - mean * mean;
        psum[0][t] = mean;
        psq[0][t] = rsqrtf(var + 1e-5f);
    }
    __syncthreads();
    int mvE = mvp[2];
#pragma unroll
    for (int i = 0; i < 2; i++) {
#pragma unroll
        for (int r = 0; r < 4; r++) {
            int rloc = i * 16 + quad * 4 + r;
            long grow = m0 + rloc;
            float mean = psum[0][rloc], rstd = psq[0][rloc];
#pragma unroll
            for (int j = 0; j < 4; j++) {
                int col = wv * 64 + j * 16 + l16;
                float y = (acc[i][j][r] - mean) * rstd * gs[col] + bs[col];
                if (rcIn) y += rcIn[grow * 256 + col];
                if (rcOut) rcOut[grow * 256 + col] = y;
                if (outSc && grow < mvE) outSc[(long)glp[grow] * 256 + col] = y;
                if (outB) outB[grow * 256 + col] = f2b(y);
            }
        }
    }
}

// ---------------- per-class KV / Ksum reduction (compact contiguous) ---------
__global__ __launch_bounds__(256) void lft_kv_kernel(
    const float* __restrict__ phik, const float* __restrict__ vmat,
    const int* __restrict__ cmetaS,
    float* kv, float* ksum)
{
    int chunk = blockIdx.x, c = blockIdx.y;
    int b = blockIdx.z >> 3, h = blockIdx.z & 7;
    int cstart = cmetaS[(b * 8 + c) * 2], n = cmetaS[(b * 8 + c) * 2 + 1];
    int per = (n + KV_NCH - 1) / KV_NCH;
    int s0 = chunk * per;
    int s1 = min(s0 + per, n);
    if (s0 >= s1) return;
    int t = threadIdx.x;
    __shared__ float kb[8][32];
    __shared__ float vb[8][32];
    int od = t >> 3, oe = (t & 7) << 2;
    int lt = t >> 5, ld = t & 31;
    float a0 = 0.f, a1 = 0.f, a2 = 0.f, a3 = 0.f, ak = 0.f;
    for (int s = s0; s < s1; s += 8) {
        float kval = 0.f, vval = 0.f;
        if (s + lt < s1) {
            long bse = (long)(cstart + s + lt) * 256 + h * 32 + ld;
            kval = phik[bse];
            vval = vmat[bse];
        }
        __syncthreads();
        kb[lt][ld] = kval;
        vb[lt][ld] = vval;
        __syncthreads();
#pragma unroll
        for (int j = 0; j < 8; j++) {
            float kd = kb[j][od];
            float4 vv = *(const float4*)&vb[j][oe];
            a0 += kd * vv.x; a1 += kd * vv.y; a2 += kd * vv.z; a3 += kd * vv.w;
            ak += kd;
        }
    }
    float* dst = kv + (((long)(b * NPROTO + c) * 8 + h) << 10) + od * 32 + oe;
    atomicAdd(dst + 0, a0);
    atomicAdd(dst + 1, a1);
    atomicAdd(dst + 2, a2);
    atomicAdd(dst + 3, a3);
    if ((t & 7) == 0)
        atomicAdd(ksum + (((long)(b * NPROTO + c) * 8 + h) << 5) + od, ak);
}

// ---------------- kv fp32 [d][e] + ksum → bf16 B-layout [e'][d], e'<48 -------
__global__ __launch_bounds__(256) void lft_kvconv_kernel(
    const float* __restrict__ kvb, const float* __restrict__ ksb,
    ushort* __restrict__ kvt)
{
    int bc = blockIdx.x;          // b*8+c
    int t = threadIdx.x;
    int h = t >> 5, d = t & 31;
    const float* kvsrc = kvb + ((long)bc * 8 + h) * 1024;
    const float* kssrc = ksb + ((long)bc * 8 + h) * 32;
    ushort* dst = kvt + ((long)bc * 8 + h) * 1536;
#pragma unroll
    for (int e = 0; e < 32; e++) dst[e * 32 + d] = f2b(kvsrc[d * 32 + e]);
    dst[32 * 32 + d] = f2b(kssrc[d]);
#pragma unroll
    for (int e = 33; e < 48; e++) dst[e * 32 + d] = 0;
}

// ---------------- msg via MFMA over compact contiguous rows ------------------
__global__ __launch_bounds__(256) void lft_msg_kernel(
    const ushort* __restrict__ pq, const ushort* __restrict__ kvt,
    const int* __restrict__ cmetaX,
    ushort* __restrict__ msg)
{
    int chunk = blockIdx.x, c = blockIdx.y, b = blockIdx.z;
    int cstart = cmetaX[(b * 8 + c) * 2], n = cmetaX[(b * 8 + c) * 2 + 1];
    int per = (n + MSG_NCH - 1) / MSG_NCH;
    int s0 = chunk * per, s1 = min(s0 + per, n);
    if (s0 >= s1) return;
    int t = threadIdx.x;
    int wave = t >> 6, lane = t & 63;
    int l16 = lane & 15, quad = lane >> 4;
    int bc = b * 8 + c;
    short8 bfr[2][3];
#pragma unroll
    for (int hh = 0; hh < 2; hh++) {
        int h = wave * 2 + hh;
        const ushort* kb = kvt + ((long)bc * 8 + h) * 1536;
#pragma unroll
        for (int nt = 0; nt < 3; nt++)
            bfr[hh][nt] = *(const short8*)&kb[(nt * 16 + l16) * 32 + quad * 8];
    }
    for (int s = s0; s < s1; s += 16) {
        long rowA = cstart + min(s + l16, s1 - 1);
#pragma unroll
        for (int hh = 0; hh < 2; hh++) {
            int h = wave * 2 + hh;
            short8 a = *(const short8*)&pq[rowA * 256 + h * 32 + quad * 8];
            floatx4 n0 = {}, n1 = {}, dd = {};
            n0 = __builtin_amdgcn_mfma_f32_16x16x32_bf16(a, bfr[hh][0], n0, 0, 0, 0);
            n1 = __builtin_amdgcn_mfma_f32_16x16x32_bf16(a, bfr[hh][1], n1, 0, 0, 0);
            dd = __builtin_amdgcn_mfma_f32_16x16x32_bf16(a, bfr[hh][2], dd, 0, 0, 0);
#pragma unroll
            for (int r = 0; r < 4; r++) {
                int rowi = s + quad * 4 + r;
                float den = __shfl(dd[r], lane & 48, 64);
                float inv = 1.f / (den + 1e-6f);
                if (rowi < s1) {
                    long base = (long)(cstart + rowi) * 256 + h * 32;
                    msg[base + l16]      = f2b(n0[r] * inv);
                    msg[base + 16 + l16] = f2b(n1[r] * inv);
                }
            }
        }
    }
}

extern "C" void kernel_launch(void* const* d_in, const int* in_sizes, int n_in,
                              void* d_out, int out_size, void* d_ws, size_t ws_size,
                              hipStream_t stream)
{
    (void)in_sizes; (void)n_in; (void)out_size; (void)ws_size;
    const float* feat0 = (const float*)d_in[0];
    const float* feat1 = (const float*)d_in[1];
    const int*   mask0 = (const int*)d_in[2];
    const int*   mask1 = (const int*)d_in[3];
    const float* f0wo  = (const float*)d_in[4];
    const float* f1wo  = (const float*)d_in[5];
    const float* proto = (const float*)d_in[6];
    const float* Wq = (const float*)d_in[7];
    const float* Wk = (const float*)d_in[8];
    const float* Wv = (const float*)d_in[9];
    const float* Wm = (const float*)d_in[10];
    const float* W1 = (const float*)d_in[11];
    const float* W2 = (const float*)d_in[12];
    const float* g1 = (const float*)d_in[13];
    const float* b1 = (const float*)d_in[14];
    const float* g2 = (const float*)d_in[15];
    const float* b2 = (const float*)d_in[16];
    float* out = (float*)d_out;
    float* ws = (float*)d_ws;

    // ---- workspace layout (compact row space, strides unchanged) ----
    const long FSZ = 9830400L;           // 8*4800*256
    float* rc0  = ws;                    // compact fp32 residual side0
    float* rc1  = ws + FSZ;              // compact fp32 residual side1
    float* kc   = ws + 2 * FSZ;          // compact phi_k fp32
    float* vc   = ws + 3 * FSZ;          // compact v fp32 ; reused as hid bf16
    ushort* ub  = (ushort*)(ws + 4 * FSZ);
    ushort* xc0  = ub;                   // compact bf16 x side0
    ushort* xc1  = ub + FSZ;
    ushort* msgc = ub + 2 * FSZ;         // compact msg bf16
    ushort* qc   = ub + 3 * FSZ;         // compact phi_q bf16
    ushort* wb   = ub + 4 * FSZ;
    ushort* wb1  = wb + 16 * 65536;
    ushort* wb2  = wb1 + 4 * 262144;
    ushort* kvt  = wb2 + 4 * 131072;
    float* kvb = (float*)(kvt + 786432);
    float* ksb = kvb + 524288;
    int* cls0 = (int*)(ksb + 16384);
    int* cls1 = cls0 + 38400;
    int* gl0  = cls1 + 38400;            // compact gather lists (were tl0/tl1)
    int* gl1  = gl0 + 38400;
    int* meta = gl1 + 38400;             // [2][8][8][2] (base,cnt)
    int* minfo = meta + 256;             // 20 ints
    int* cmeta = minfo + 20;             // [2][8][8][2] compact (start,cnt)
    ushort* hid = (ushort*)vc;           // compact [*,512] bf16 (reuses vc)

    lft_wconv_kernel<<<dim3(8, 8, 16), 256, 0, stream>>>(Wq, Wk, Wv, Wm, 256, 256, 4, wb);
    lft_wconv_kernel<<<dim3(16, 16, 4), 256, 0, stream>>>(W1, W1, W1, W1, 512, 512, 1, wb1);
    lft_wconv_kernel<<<dim3(16, 8, 4), 256, 0, stream>>>(W2, W2, W2, W2, 512, 256, 1, wb2);
    // prefill final outputs: invalid tokens pass through untouched
    hipMemcpyAsync(out, feat0, FSZ * 4, hipMemcpyDeviceToDevice, stream);
    hipMemcpyAsync(out + FSZ, feat1, FSZ * 4, hipMemcpyDeviceToDevice, stream);
    hipMemcpyAsync(out + 20352000L, proto, 2048 * 4, hipMemcpyDeviceToDevice, stream);
    lft_class_kernel<<<300, 256, 0, stream>>>(f0wo, f1wo, mask0, mask1, proto,
                                              out, cls0, cls1);
    lft_count_kernel<<<16, 256, 0, stream>>>(cls0, cls1, meta);
    lft_scan_kernel<<<1, 256, 0, stream>>>(meta, minfo, cmeta);
    lft_place_kernel<<<16, 256, 0, stream>>>(cls0, cls1, cmeta, gl0, gl1);
    lft_gcast_kernel<<<1200, 256, 0, stream>>>(feat0, feat1, gl0, gl1, minfo,
                                               xc0, xc1, rc0, rc1);

    const int* mvp0 = minfo;        // [0]=mv0 rnd, [2]=mv0
    const int* mvp1 = minfo + 1;    // [0]=mv1 rnd, [2]=mv1
    const int* cm0 = cmeta;
    const int* cm1 = cmeta + 128;

    for (int li = 0; li < 4; li++) {
        const ushort* wq = wb + (size_t)(li * 4 + 0) * 65536;   // [wq|wk|wv|wm] contiguous
        const ushort* wk = wb + (size_t)(li * 4 + 1) * 65536;
        const ushort* wm = wb + (size_t)(li * 4 + 3) * 65536;
        const ushort* w1 = wb1 + (size_t)li * 262144;
        const ushort* w2 = wb2 + (size_t)li * 131072;
        const float* g1p = g1 + li * 256; const float* b1p = b1 + li * 256;
        const float* g2p = g2 + li * 256; const float* b2p = b2 + li * 256;

        auto call = [&](ushort* xcX, ushort* xcS,
                        const int* mvpX, const int* mvpS,
                        const int* cmX, const int* cmS,
                        const int* glX, float* rcX,
                        float* outX, ushort* lastB, bool selfself) {
            dim3 blk(256);
            if (selfself) {
                lft_mfma_gemm<<<dim3(6, 300), blk, 0, stream>>>(
                    xcX, xcX, 256, wq, kc, qc, vc, 768, 256, 3, mvpX);
            } else {
                lft_mfma_gemm<<<dim3(2, 300), blk, 0, stream>>>(
                    xcX, xcX, 256, wq, nullptr, qc, nullptr, 256, 256, 1, mvpX);
                lft_mfma_gemm<<<dim3(4, 300), blk, 0, stream>>>(
                    xcS, xcS, 256, wk, kc, nullptr, vc, 512, 256, 4, mvpS);
            }
            hipMemsetAsync(kvb, 0, (524288 + 16384) * 4, stream);
            lft_kv_kernel<<<dim3(KV_NCH, 8, 64), blk, 0, stream>>>(kc, vc, cmS, kvb, ksb);
            lft_kvconv_kernel<<<64, blk, 0, stream>>>(kvb, ksb, kvt);
            lft_msg_kernel<<<dim3(MSG_NCH, 8, 8), blk, 0, stream>>>(qc, kvt, cmX, msgc);
            // msg = LN(msg @ Wm)*g1+b1  (compact, in-place bf16)
            lft_gemm_ln<<<1200, blk, 0, stream>>>(msgc, msgc, 256, wm, 256,
                                                  g1p, b1p, nullptr, nullptr,
                                                  nullptr, mvpX, nullptr, msgc);
            // hid = relu([x|msg]@W1) (compact)
            lft_mfma_gemm<<<dim3(4, 300), blk, 0, stream>>>(
                xcX, msgc, 256, w1, nullptr, hid, nullptr, 512, 512, 2, mvpX);
            // y = resid + LN(hid@W2)
            if (!outX) {
                lft_gemm_ln<<<1200, blk, 0, stream>>>(hid, hid, 512, w2, 512,
                                                      g2p, b2p, rcX, rcX,
                                                      nullptr, mvpX, nullptr, xcX);
            } else {
                lft_gemm_ln<<<1200, blk, 0, stream>>>(hid, hid, 512, w2, 512,
                                                      g2p, b2p, rcX, nullptr,
                                                      glX, mvpX, outX, lastB);
            }
        };

        if ((li & 1) == 0) {           // self-self (never the last layer)
            call(xc0, xc0, mvp0, mvp0, cm0, cm0, gl0, rc0, nullptr, nullptr, true);
            call(xc1, xc1, mvp1, mvp1, cm1, cm1, gl1, rc1, nullptr, nullptr, true);
        } else if (li == 1) {          // cross-self
            call(xc0, xc1, mvp0, mvp1, cm0, cm1, gl0, rc0, nullptr, nullptr, false);
            call(xc1, xc0, mvp1, mvp0, cm1, cm0, gl1, rc1, nullptr, nullptr, false);
        } else {                       // li == 3: cross-self, final layer
            // side0 must still publish updated bf16 (src for side1's kv)
            call(xc0, xc1, mvp0, mvp1, cm0, cm1, gl0, rc0, out, xc0, false);
            call(xc1, xc0, mvp1, mvp0, cm1, cm0, gl1, rc1, out + FSZ, nullptr, false);
        }
    }
}

// Round 10
// 1459.096 us; speedup vs baseline: 1.9066x; 1.0852x over previous
//
#include <hip/hip_runtime.h>
#include <math.h>

#define NPROTO 8
#define KV_NCH 4
#define MSG_NCH 8
#define CAP 24576L            // compact rows per side (Mv ~= 19200 +- ~200)

typedef __attribute__((ext_vector_type(8))) short short8;
typedef __attribute__((ext_vector_type(4))) float floatx4;

static __device__ __forceinline__ ushort f2b(float f) {
    unsigned u = __builtin_bit_cast(unsigned, f);
    unsigned r = (u + 0x7fffu + ((u >> 16) & 1u)) >> 16;
    return (ushort)r;
}

static __device__ __forceinline__ float elu1(float v) {
    return v > 0.f ? v + 1.f : __expf(v);
}

// async 16B global -> LDS (linear dest: wave base + lane*16B)
#define GLOAD16(gp, lp) __builtin_amdgcn_global_load_lds( \
    (const __attribute__((address_space(1))) void*)(gp),  \
    (__attribute__((address_space(3))) void*)(lp), 16, 0, 0)

// drain staging loads + retire LDS reads, then raw barrier (memory-fenced)
#define WAIT_BAR() asm volatile("s_waitcnt vmcnt(0) lgkmcnt(0)\n\ts_barrier" ::: "memory")

// swizzle of the 16B-group index within a 32-col bf16 row (4 groups/row)
static __device__ __forceinline__ int swz(int r) { return (r >> 1) & 3; }

// ---------------- prototype projection / argmax-class kernel ----------------
// 128 tokens/block (grid 600), 2 threads per token (4 protos each),
// LDS tile stride 68 floats (full-throughput b128 reads), 47KB -> 3 blocks/CU.
__global__ __launch_bounds__(256) void lft_class_kernel(
    const float* __restrict__ f0wo, const float* __restrict__ f1wo,
    const int* __restrict__ mask0, const int* __restrict__ mask1,
    const float* __restrict__ proto,
    float* out, int* cls0, int* cls1)
{
    __shared__ float pr[2048];          // proto [8][256]
    __shared__ float tile[128][68];     // [token][ch chunk], stride 68
    __shared__ float sm[128][8];
    int t = threadIdx.x;
    *(float4*)&pr[t * 4]        = *(const float4*)&proto[t * 4];
    *(float4*)&pr[1024 + t * 4] = *(const float4*)&proto[1024 + t * 4];
    long tok0 = (long)blockIdx.x * 128;
    const float* fsrc; const int* msrc; float* fpout; float* clsout; int* clsarr; long tbase;
    if (tok0 < 38400) {
        tbase = tok0; fsrc = f0wo; msrc = mask0;
        fpout = out + 19737600L; clsout = out + 19660800L; clsarr = cls0;
    } else {
        tbase = tok0 - 38400; fsrc = f1wo; msrc = mask1;
        fpout = out + 20044800L; clsout = out + 19699200L; clsarr = cls1;
    }
    int tok = t & 127, half = t >> 7;
    float s[4] = {};
    int r0 = t >> 4;            // 0..15
    int c4 = (t & 15) << 2;     // 0..60
    for (int ct = 0; ct < 4; ct++) {
        __syncthreads();
#pragma unroll
        for (int rr = 0; rr < 8; rr++) {
            int row = rr * 16 + r0;
            float4 v = *(const float4*)&fsrc[(tbase + row) * 256 + ct * 64 + c4];
            *(float4*)&tile[row][c4] = v;
        }
        __syncthreads();
#pragma unroll
        for (int cc = 0; cc < 16; cc++) {
            float4 f = *(const float4*)&tile[tok][cc << 2];
#pragma unroll
            for (int p = 0; p < 4; p++) {
                float4 pv = *(const float4*)&pr[(half * 4 + p) * 256 + ct * 64 + (cc << 2)];
                s[p] += f.x * pv.x + f.y * pv.y + f.z * pv.z + f.w * pv.w;
            }
        }
    }
#pragma unroll
    for (int p = 0; p < 4; p++) {
        fpout[(tbase + tok) * 8 + half * 4 + p] = s[p];
        sm[tok][half * 4 + p] = s[p];
    }
    __syncthreads();
    if (t < 128) {
        int best = 0; float bv = sm[t][0];
#pragma unroll
        for (int p = 1; p < 8; p++) { if (sm[t][p] > bv) { bv = sm[t][p]; best = p; } }
        clsout[tbase + t] = (float)best;
        clsarr[tbase + t] = msrc[tbase + t] ? best : -1;
    }
}

// ---------------- per-(L,b) class counts -> meta {base,cnt} ------------------
__global__ __launch_bounds__(256) void lft_count_kernel(
    const int* __restrict__ cls0, const int* __restrict__ cls1, int* meta)
{
    int g = blockIdx.x; int L = g >> 3, b = g & 7;
    const int* cls = (L ? cls1 : cls0) + b * 4800;
    int* mt = meta + (L * 8 + b) * 16;
    __shared__ int cnt[8];
    int t = threadIdx.x;
    if (t < 8) cnt[t] = 0;
    __syncthreads();
    for (int tok = t; tok < 4800; tok += 256) {
        int c = cls[tok];
        if (c >= 0) atomicAdd(&cnt[c], 1);
    }
    __syncthreads();
    if (t == 0) {
        int s = 0;
        for (int c = 0; c < 8; c++) { mt[c * 2] = s; mt[c * 2 + 1] = cnt[c]; s += cnt[c]; }
    }
}

// ---------------- cross-batch scan: minfo (Mv, boff) + compact cmeta ---------
// minfo: [0]=mv0 rnd128, [1]=mv1 rnd128, [2]=mv0, [3]=mv1, [4..11]=boff0, [12..19]=boff1
__global__ __launch_bounds__(256) void lft_scan_kernel(
    const int* __restrict__ meta, int* minfo, int* cmeta)
{
    int t = threadIdx.x;
    __shared__ int nb[16];
    if (t < 16) {
        int s = 0;
        for (int c = 0; c < 8; c++) s += meta[t * 16 + c * 2 + 1];
        nb[t] = s;
    }
    __syncthreads();
    if (t == 0) {
        int off = 0;
        for (int b = 0; b < 8; b++) { minfo[4 + b] = off; off += nb[b]; }
        minfo[2] = off; minfo[0] = (off + 127) & ~127;
        off = 0;
        for (int b = 0; b < 8; b++) { minfo[12 + b] = off; off += nb[8 + b]; }
        minfo[3] = off; minfo[1] = (off + 127) & ~127;
    }
    __syncthreads();
    if (t < 128) {
        int L = t >> 6, b = (t >> 3) & 7, c = t & 7;
        cmeta[t * 2]     = minfo[4 + L * 8 + b] + meta[(L * 8 + b) * 16 + c * 2];
        cmeta[t * 2 + 1] = meta[(L * 8 + b) * 16 + c * 2 + 1];
    }
}

// ---------------- place valid tokens into compact gather lists ---------------
__global__ __launch_bounds__(256) void lft_place_kernel(
    const int* __restrict__ cls0, const int* __restrict__ cls1,
    const int* __restrict__ cmeta, int* gl)
{
    int g = blockIdx.x; int L = g >> 3, b = g & 7;
    const int* cls = (L ? cls1 : cls0) + b * 4800;
    int* glp = gl + L * CAP;
    __shared__ int pos[8];
    int t = threadIdx.x;
    if (t < 8) pos[t] = cmeta[(L * 64 + b * 8 + t) * 2];
    __syncthreads();
    for (int tok = t; tok < 4800; tok += 256) {
        int c = cls[tok];
        if (c >= 0) { int p = atomicAdd(&pos[c], 1); glp[p] = b * 4800 + tok; }
    }
}

// ---------------- gather-cast: compact bf16 x + compact fp32 resid -----------
__global__ __launch_bounds__(256) void lft_gcast_kernel(
    const float* __restrict__ f0, const float* __restrict__ f1,
    const int* __restrict__ gl, const int* __restrict__ minfo,
    ushort* xc, float* rc)
{
    int blk = blockIdx.x;
    int side = blk >= 600 ? 1 : 0;
    int i0 = (blk - side * 600) * 4 + (threadIdx.x >> 6);
    int mv = minfo[2 + side];
    const int* glp = gl + side * CAP;
    const float* f = side ? f1 : f0;
    ushort* xcp = xc + side * CAP * 256;
    float* rcp = rc + side * CAP * 256;
    int lane = threadIdx.x & 63;
    for (int i = i0; i < mv; i += 2400) {
        long src = (long)glp[i] * 256 + lane * 4;
        float4 v = *(const float4*)&f[src];
        long dst = (long)i * 256 + lane * 4;
        *(float4*)&rcp[dst] = v;
        ushort4 u; u.x = f2b(v.x); u.y = f2b(v.y); u.z = f2b(v.z); u.w = f2b(v.w);
        *(ushort4*)&xcp[dst] = u;
    }
}

// ---------------- weight convert + transpose: Wt[n*K+k] = bf16(W[k*N+n]) ----
__global__ __launch_bounds__(256) void lft_wconv_kernel(
    const float* W0, const float* W1p, const float* W2p, const float* W3p,
    int K, int N, int nTypes, ushort* dst)
{
    int z = blockIdx.z;
    int li = z / nTypes, mi = z % nTypes;
    const float* srcs[4] = {W0, W1p, W2p, W3p};
    const float* src = srcs[mi] + (size_t)li * K * N;
    ushort* outp = dst + (size_t)z * K * N;
    __shared__ float tile[32][33];
    int k0 = blockIdx.x * 32, n0 = blockIdx.y * 32;
    int t = threadIdx.x;
    int r = t >> 3, c4 = (t & 7) << 2;
    float4 v = *(const float4*)&src[(size_t)(k0 + r) * N + n0 + c4];
    tile[r][c4] = v.x; tile[r][c4 + 1] = v.y; tile[r][c4 + 2] = v.z; tile[r][c4 + 3] = v.w;
    __syncthreads();
    ushort4 o;
    o.x = f2b(tile[c4 + 0][r]);
    o.y = f2b(tile[c4 + 1][r]);
    o.z = f2b(tile[c4 + 2][r]);
    o.w = f2b(tile[c4 + 3][r]);
    *(ushort4*)&outp[(size_t)(n0 + r) * K + k0 + c4] = o;
}

// ---------------- bf16 MFMA GEMM over COMPACT rows, side = blockIdx.z --------
// R2-proven 2-phase drain pipeline, 128x128 tile, 4 waves. side = side0 + z.
// act: 0 none, 1 elu+1, 2 relu; act 3 qkv N=768; act 4 kv N=512.
__global__ __launch_bounds__(256) void lft_mfma_gemm(
    const ushort* __restrict__ A0b, const ushort* __restrict__ A1b, int kSplit,
    const ushort* __restrict__ Wt,
    float* Cf, ushort* Cb, float* Cv, int N, int K, int act,
    const int* __restrict__ minfo, int side0)
{
    __shared__ ushort As[2][128 * 32];
    __shared__ ushort Bs[2][128 * 32];
    int side = side0 + blockIdx.z;
    int m0 = blockIdx.y << 7;
    if (m0 >= minfo[side]) return;
    const ushort* A0 = A0b + (long)side * CAP * kSplit;
    const ushort* A1 = A1b + (long)side * CAP * (K - kSplit);
    long so256 = (long)side * CAP * 256;
    long soN = (long)side * CAP * N;
    int t = threadIdx.x;
    int n0 = blockIdx.x << 7;
    int wv = t >> 6, lane = t & 63;
    int wm = wv >> 1, wn = wv & 1;
    int l16 = lane & 15, quad = lane >> 4;
    floatx4 acc[4][4] = {};

    int lrow = lane >> 2;
    int lcg = lane & 3;

    auto stage = [&](int buf, int k0) {
        const ushort* Asrc; int kcol, ldA;
        if (k0 < kSplit) { Asrc = A0; kcol = k0;          ldA = kSplit; }
        else             { Asrc = A1; kcol = k0 - kSplit; ldA = K - kSplit; }
        ushort* Ab = &As[buf][0];
        ushort* Bb = &Bs[buf][0];
#pragma unroll
        for (int s = 0; s < 2; s++) {
            int r = s * 64 + wv * 16 + lrow;
            int cgA = (lcg ^ swz(r)) << 3;
            GLOAD16(&Asrc[(size_t)(m0 + r) * ldA + kcol + cgA], &Ab[(s * 64 + wv * 16) * 32]);
            GLOAD16(&Wt[(size_t)(n0 + r) * K + k0 + cgA], &Bb[(s * 64 + wv * 16) * 32]);
        }
    };

    int nt = K >> 5;
    stage(0, 0);
    WAIT_BAR();
    int cur = 0;
    for (int tt = 0; tt < nt; ++tt) {
        if (tt + 1 < nt) stage(cur ^ 1, (tt + 1) << 5);
        const ushort* Ab = &As[cur][0];
        const ushort* Bb = &Bs[cur][0];
        short8 af[4], bfr[4];
#pragma unroll
        for (int i = 0; i < 4; i++) {
            int rA = wm * 64 + i * 16 + l16;
            int rB = wn * 64 + i * 16 + l16;
            af[i]  = *(const short8*)&Ab[rA * 32 + ((quad ^ swz(rA)) << 3)];
            bfr[i] = *(const short8*)&Bb[rB * 32 + ((quad ^ swz(rB)) << 3)];
        }
#pragma unroll
        for (int i = 0; i < 4; i++)
#pragma unroll
            for (int j = 0; j < 4; j++)
                acc[i][j] = __builtin_amdgcn_mfma_f32_16x16x32_bf16(af[i], bfr[j], acc[i][j], 0, 0, 0);
        if (tt + 1 < nt) { WAIT_BAR(); cur ^= 1; }
    }
#pragma unroll
    for (int i = 0; i < 4; i++) {
#pragma unroll
        for (int j = 0; j < 4; j++) {
#pragma unroll
            for (int r = 0; r < 4; r++) {
                float v = acc[i][j][r];
                long row = m0 + wm * 64 + i * 16 + quad * 4 + r;
                int col = n0 + wn * 64 + j * 16 + l16;
                if (act == 3) {
                    if (col < 256)      Cb[so256 + row * 256 + col] = f2b(elu1(v));
                    else if (col < 512) Cf[so256 + row * 256 + col - 256] = elu1(v);
                    else                Cv[so256 + row * 256 + col - 512] = v;
                } else if (act == 4) {
                    if (col < 256) Cf[so256 + row * 256 + col] = elu1(v);
                    else           Cv[so256 + row * 256 + col - 256] = v;
                } else {
                    if (act == 1)      v = elu1(v);
                    else if (act == 2) v = fmaxf(v, 0.f);
                    if (Cf) Cf[soN + row * N + col] = v;
                    if (Cb) Cb[soN + row * N + col] = f2b(v);
                }
            }
        }
    }
}

// ---------------- fused GEMM (N=256) + row-LN over COMPACT rows -------------
// M=32 tile (grid.x=768 per side, early-exit); side = side0 + blockIdx.z.
__global__ __launch_bounds__(256) void lft_gemm_ln(
    const ushort* __restrict__ A0b, const ushort* __restrict__ A1b, int kSplit,
    const ushort* __restrict__ Wt, int K,
    const float* __restrict__ g, const float* __restrict__ bb,
    const float* __restrict__ rcInB, float* rcOutB,
    const int* __restrict__ glB, const int* __restrict__ minfo,
    float* outScB, ushort* __restrict__ outBB, int side0)
{
    __shared__ ushort As[2][32 * 32];
    __shared__ ushort Bs[2][256 * 32];
    __shared__ float gs[256], bs[256];
    __shared__ float psum[4][32], psq[4][32];
    int side = side0 + blockIdx.z;
    long m0 = (long)blockIdx.x << 5;
    if (m0 >= minfo[side]) return;
    const ushort* A0 = A0b + (long)side * CAP * kSplit;
    const ushort* A1 = A1b + (long)side * CAP * (K - kSplit);
    long so = (long)side * CAP * 256;
    int t = threadIdx.x;
    int wv = t >> 6, lane = t & 63;
    int l16 = lane & 15, quad = lane >> 4;
    gs[t] = g[t]; bs[t] = bb[t];
    floatx4 acc[2][4] = {};

    int lrow = lane >> 2;
    int lcg = lane & 3;

    auto stage = [&](int buf, int k0) {
        const ushort* Asrc; int kcol, ldA;
        if (k0 < kSplit) { Asrc = A0; kcol = k0;          ldA = kSplit; }
        else             { Asrc = A1; kcol = k0 - kSplit; ldA = K - kSplit; }
        if (wv < 2) {
            int r = wv * 16 + lrow;
            int cgA = (lcg ^ swz(r)) << 3;
            GLOAD16(&Asrc[(m0 + r) * ldA + kcol + cgA], &As[buf][(wv * 16) * 32]);
        }
#pragma unroll
        for (int s = 0; s < 4; s++) {
            int r = s * 64 + wv * 16 + lrow;
            int cgB = (lcg ^ swz(r)) << 3;
            GLOAD16(&Wt[(size_t)r * K + k0 + cgB], &Bs[buf][(s * 64 + wv * 16) * 32]);
        }
    };

    int nt = K >> 5;
    stage(0, 0);
    WAIT_BAR();
    int cur = 0;
    for (int tt = 0; tt < nt; ++tt) {
        if (tt + 1 < nt) stage(cur ^ 1, (tt + 1) << 5);
        const ushort* Ab = &As[cur][0];
        const ushort* Bb = &Bs[cur][0];
        short8 af[2], bfr[4];
#pragma unroll
        for (int i = 0; i < 2; i++) {
            int rA = i * 16 + l16;
            af[i] = *(const short8*)&Ab[rA * 32 + ((quad ^ swz(rA)) << 3)];
        }
#pragma unroll
        for (int j = 0; j < 4; j++) {
            int rB = wv * 64 + j * 16 + l16;
            bfr[j] = *(const short8*)&Bb[rB * 32 + ((quad ^ swz(rB)) << 3)];
        }
#pragma unroll
        for (int i = 0; i < 2; i++)
#pragma unroll
            for (int j = 0; j < 4; j++)
                acc[i][j] = __builtin_amdgcn_mfma_f32_16x16x32_bf16(af[i], bfr[j], acc[i][j], 0, 0, 0);
        if (tt + 1 < nt) { WAIT_BAR(); cur ^= 1; }
    }
#pragma unroll
    for (int i = 0; i < 2; i++) {
#pragma unroll
        for (int r = 0; r < 4; r++) {
            float s = 0.f, q = 0.f;
#pragma unroll
            for (int j = 0; j < 4; j++) { float v = acc[i][j][r]; s += v; q += v * v; }
#pragma unroll
            for (int o = 8; o >= 1; o >>= 1) {
                s += __shfl_xor(s, o, 64);
                q += __shfl_xor(q, o, 64);
            }
            if (l16 == 0) {
                int row = i * 16 + quad * 4 + r;
                psum[wv][row] = s; psq[wv][row] = q;
            }
        }
    }
    __syncthreads();
    if (t < 32) {
        float s = psum[0][t] + psum[1][t] + psum[2][t] + psum[3][t];
        float q = psq[0][t] + psq[1][t] + psq[2][t] + psq[3][t];
        float mean = s * (1.0f / 256.0f);
        float var = q * (1.0f / 256.0f) - mean * mean;
        psum[0][t] = mean;
        psq[0][t] = rsqrtf(var + 1e-5f);
    }
    __syncthreads();
    int mvE = minfo[2 + side];
    const float* rcIn = rcInB ? rcInB + so : nullptr;
    float* rcOut = rcOutB ? rcOutB + so : nullptr;
    const int* glp = glB + side * CAP;
    float* outSc = outScB ? outScB + (long)side * 9830400L : nullptr;
    ushort* outB = outBB ? outBB + so : nullptr;
#pragma unroll
    for (int i = 0; i < 2; i++) {
#pragma unroll
        for (int r = 0; r < 4; r++) {
            int rloc = i * 16 + quad * 4 + r;
            long grow = m0 + rloc;
            float mean = psum[0][rloc], rstd = psq[0][rloc];
#pragma unroll
            for (int j = 0; j < 4; j++) {
                int col = wv * 64 + j * 16 + l16;
                float y = (acc[i][j][r] - mean) * rstd * gs[col] + bs[col];
                if (rcIn) y += rcIn[grow * 256 + col];
                if (rcOut) rcOut[grow * 256 + col] = y;
                if (outSc && grow < mvE) outSc[(long)glp[grow] * 256 + col] = y;
                if (outB) outB[grow * 256 + col] = f2b(y);
            }
        }
    }
}

// ---------------- per-class KV / Ksum reduction (compact contiguous) ---------
// side = sideSrc0 + (blockIdx.z >> 6); kvb/ksb slot = side.
__global__ __launch_bounds__(256) void lft_kv_kernel(
    const float* __restrict__ kcB, const float* __restrict__ vcB,
    const int* __restrict__ cmetaB,
    float* kvbB, float* ksbB, int sideSrc0)
{
    int side = sideSrc0 + (blockIdx.z >> 6);
    int zz = blockIdx.z & 63;
    int chunk = blockIdx.x, c = blockIdx.y;
    int b = zz >> 3, h = zz & 7;
    const int* cmeta = cmetaB + side * 128;
    int cstart = cmeta[(b * 8 + c) * 2], n = cmeta[(b * 8 + c) * 2 + 1];
    int per = (n + KV_NCH - 1) / KV_NCH;
    int s0 = chunk * per;
    int s1 = min(s0 + per, n);
    if (s0 >= s1) return;
    const float* phik = kcB + (long)side * CAP * 256;
    const float* vmat = vcB + (long)side * CAP * 256;
    float* kv = kvbB + (long)side * 524288;
    float* ksum = ksbB + (long)side * 16384;
    int t = threadIdx.x;
    __shared__ float kb[8][32];
    __shared__ float vb[8][32];
    int od = t >> 3, oe = (t & 7) << 2;
    int lt = t >> 5, ld = t & 31;
    float a0 = 0.f, a1 = 0.f, a2 = 0.f, a3 = 0.f, ak = 0.f;
    for (int s = s0; s < s1; s += 8) {
        float kval = 0.f, vval = 0.f;
        if (s + lt < s1) {
            long bse = (long)(cstart + s + lt) * 256 + h * 32 + ld;
            kval = phik[bse];
            vval = vmat[bse];
        }
        __syncthreads();
        kb[lt][ld] = kval;
        vb[lt][ld] = vval;
        __syncthreads();
#pragma unroll
        for (int j = 0; j < 8; j++) {
            float kd = kb[j][od];
            float4 vv = *(const float4*)&vb[j][oe];
            a0 += kd * vv.x; a1 += kd * vv.y; a2 += kd * vv.z; a3 += kd * vv.w;
            ak += kd;
        }
    }
    float* dst = kv + (((long)(b * NPROTO + c) * 8 + h) << 10) + od * 32 + oe;
    atomicAdd(dst + 0, a0);
    atomicAdd(dst + 1, a1);
    atomicAdd(dst + 2, a2);
    atomicAdd(dst + 3, a3);
    if ((t & 7) == 0)
        atomicAdd(ksum + (((long)(b * NPROTO + c) * 8 + h) << 5) + od, ak);
}

// ---------------- msg via MFMA over compact rows; kv fragments from fp32 -----
// grid z: (sideAdd*8 + b); sideX = sideX0+add (q/msg/cmeta), sideKV = sideKV0+add.
__global__ __launch_bounds__(256) void lft_msg_kernel(
    const ushort* __restrict__ qcB, const float* __restrict__ kvbB,
    const float* __restrict__ ksbB, const int* __restrict__ cmetaB,
    ushort* __restrict__ msgcB, int sideX0, int sideKV0)
{
    int add = blockIdx.z >> 3, b = blockIdx.z & 7;
    int sideX = sideX0 + add, sideKV = sideKV0 + add;
    int chunk = blockIdx.x, c = blockIdx.y;
    const int* cmeta = cmetaB + sideX * 128;
    int cstart = cmeta[(b * 8 + c) * 2], n = cmeta[(b * 8 + c) * 2 + 1];
    int per = (n + MSG_NCH - 1) / MSG_NCH;
    int s0 = chunk * per, s1 = min(s0 + per, n);
    if (s0 >= s1) return;
    const ushort* pq = qcB + (long)sideX * CAP * 256;
    ushort* msg = msgcB + (long)sideX * CAP * 256;
    int t = threadIdx.x;
    int wave = t >> 6, lane = t & 63;
    int l16 = lane & 15, quad = lane >> 4;
    int bc = b * 8 + c;
    short8 bfr[2][3];
#pragma unroll
    for (int hh = 0; hh < 2; hh++) {
        int h = wave * 2 + hh;
        const float* kvsrc = kvbB + (long)sideKV * 524288 + ((long)bc * 8 + h) * 1024;
        const float* kssrc = ksbB + (long)sideKV * 16384 + ((long)bc * 8 + h) * 32;
#pragma unroll
        for (int nt = 0; nt < 2; nt++)
#pragma unroll
            for (int j = 0; j < 8; j++)
                bfr[hh][nt][j] = (short)f2b(kvsrc[(quad * 8 + j) * 32 + nt * 16 + l16]);
#pragma unroll
        for (int j = 0; j < 8; j++)
            bfr[hh][2][j] = (l16 == 0) ? (short)f2b(kssrc[quad * 8 + j]) : (short)0;
    }
    for (int s = s0; s < s1; s += 16) {
        long rowA = cstart + min(s + l16, s1 - 1);
#pragma unroll
        for (int hh = 0; hh < 2; hh++) {
            int h = wave * 2 + hh;
            short8 a = *(const short8*)&pq[rowA * 256 + h * 32 + quad * 8];
            floatx4 n0 = {}, n1 = {}, dd = {};
            n0 = __builtin_amdgcn_mfma_f32_16x16x32_bf16(a, bfr[hh][0], n0, 0, 0, 0);
            n1 = __builtin_amdgcn_mfma_f32_16x16x32_bf16(a, bfr[hh][1], n1, 0, 0, 0);
            dd = __builtin_amdgcn_mfma_f32_16x16x32_bf16(a, bfr[hh][2], dd, 0, 0, 0);
#pragma unroll
            for (int r = 0; r < 4; r++) {
                int rowi = s + quad * 4 + r;
                float den = __shfl(dd[r], lane & 48, 64);
                float inv = 1.f / (den + 1e-6f);
                if (rowi < s1) {
                    long base = (long)(cstart + rowi) * 256 + h * 32;
                    msg[base + l16]      = f2b(n0[r] * inv);
                    msg[base + 16 + l16] = f2b(n1[r] * inv);
                }
            }
        }
    }
}

extern "C" void kernel_launch(void* const* d_in, const int* in_sizes, int n_in,
                              void* d_out, int out_size, void* d_ws, size_t ws_size,
                              hipStream_t stream)
{
    (void)in_sizes; (void)n_in; (void)out_size; (void)ws_size;
    const float* feat0 = (const float*)d_in[0];
    const float* feat1 = (const float*)d_in[1];
    const int*   mask0 = (const int*)d_in[2];
    const int*   mask1 = (const int*)d_in[3];
    const float* f0wo  = (const float*)d_in[4];
    const float* f1wo  = (const float*)d_in[5];
    const float* proto = (const float*)d_in[6];
    const float* Wq = (const float*)d_in[7];
    const float* Wk = (const float*)d_in[8];
    const float* Wv = (const float*)d_in[9];
    const float* Wm = (const float*)d_in[10];
    const float* W1 = (const float*)d_in[11];
    const float* W2 = (const float*)d_in[12];
    const float* g1 = (const float*)d_in[13];
    const float* b1 = (const float*)d_in[14];
    const float* g2 = (const float*)d_in[15];
    const float* b2 = (const float*)d_in[16];
    float* out = (float*)d_out;
    float* ws = (float*)d_ws;

    // ---- workspace layout (side-strided compact buffers, CAP rows/side) ----
    const long FSZ = 9830400L;
    float* rc = ws;                               // 2*CAP*256 f
    float* kc = rc + 2 * CAP * 256;               // 2*CAP*256 f
    float* vc = kc + 2 * CAP * 256;               // 2*CAP*256 f (reused as hid)
    ushort* xc   = (ushort*)(vc + 2 * CAP * 256); // 2*CAP*256 us
    ushort* msgc = xc + 2 * CAP * 256;
    ushort* qc   = msgc + 2 * CAP * 256;
    ushort* wb   = qc + 2 * CAP * 256;
    ushort* wb1  = wb + 16 * 65536;
    ushort* wb2  = wb1 + 4 * 262144;
    float* kvb = (float*)(wb2 + 4 * 131072);      // 2*524288 f
    float* ksb = kvb + 2 * 524288;                // 2*16384 f
    int* cls0 = (int*)(ksb + 2 * 16384);
    int* cls1 = cls0 + 38400;
    int* gl   = cls1 + 38400;                     // 2*CAP ints
    int* meta = gl + 2 * CAP;
    int* minfo = meta + 256;
    int* cmeta = minfo + 20;
    ushort* hid = (ushort*)vc;                    // 2*CAP*512 us

    lft_wconv_kernel<<<dim3(8, 8, 16), 256, 0, stream>>>(Wq, Wk, Wv, Wm, 256, 256, 4, wb);
    lft_wconv_kernel<<<dim3(16, 16, 4), 256, 0, stream>>>(W1, W1, W1, W1, 512, 512, 1, wb1);
    lft_wconv_kernel<<<dim3(16, 8, 4), 256, 0, stream>>>(W2, W2, W2, W2, 512, 256, 1, wb2);
    hipMemcpyAsync(out, feat0, FSZ * 4, hipMemcpyDeviceToDevice, stream);
    hipMemcpyAsync(out + FSZ, feat1, FSZ * 4, hipMemcpyDeviceToDevice, stream);
    hipMemcpyAsync(out + 20352000L, proto, 2048 * 4, hipMemcpyDeviceToDevice, stream);
    lft_class_kernel<<<600, 256, 0, stream>>>(f0wo, f1wo, mask0, mask1, proto,
                                              out, cls0, cls1);
    lft_count_kernel<<<16, 256, 0, stream>>>(cls0, cls1, meta);
    lft_scan_kernel<<<1, 256, 0, stream>>>(meta, minfo, cmeta);
    lft_place_kernel<<<16, 256, 0, stream>>>(cls0, cls1, cmeta, gl);
    lft_gcast_kernel<<<1200, 256, 0, stream>>>(feat0, feat1, gl, minfo, xc, rc);

    dim3 blk(256);
    for (int li = 0; li < 4; li++) {
        const ushort* wq = wb + (size_t)(li * 4 + 0) * 65536;   // [wq|wk|wv|wm]
        const ushort* wk = wb + (size_t)(li * 4 + 1) * 65536;
        const ushort* wm = wb + (size_t)(li * 4 + 3) * 65536;
        const ushort* w1 = wb1 + (size_t)li * 262144;
        const ushort* w2 = wb2 + (size_t)li * 131072;
        const float* g1p = g1 + li * 256; const float* b1p = b1 + li * 256;
        const float* g2p = g2 + li * 256; const float* b2p = b2 + li * 256;
        bool last = (li == 3);

        if ((li & 1) == 0) {
            // ---- self-self, both sides combined (z=2) ----
            lft_mfma_gemm<<<dim3(6, 192, 2), blk, 0, stream>>>(
                xc, xc, 256, wq, kc, qc, vc, 768, 256, 3, minfo, 0);
            hipMemsetAsync(kvb, 0, (2 * 524288 + 2 * 16384) * 4, stream);
            lft_kv_kernel<<<dim3(KV_NCH, 8, 128), blk, 0, stream>>>(kc, vc, cmeta, kvb, ksb, 0);
            lft_msg_kernel<<<dim3(MSG_NCH, 8, 16), blk, 0, stream>>>(qc, kvb, ksb, cmeta, msgc, 0, 0);
            lft_gemm_ln<<<dim3(768, 1, 2), blk, 0, stream>>>(
                msgc, msgc, 256, wm, 256, g1p, b1p,
                nullptr, nullptr, gl, minfo, nullptr, msgc, 0);
            lft_mfma_gemm<<<dim3(4, 192, 2), blk, 0, stream>>>(
                xc, msgc, 256, w1, nullptr, hid, nullptr, 512, 512, 2, minfo, 0);
            lft_gemm_ln<<<dim3(768, 1, 2), blk, 0, stream>>>(
                hid, hid, 512, w2, 512, g2p, b2p,
                rc, rc, gl, minfo, nullptr, xc, 0);
        } else {
            // ---- cross-self: q for both sides from OLD features ----
            lft_mfma_gemm<<<dim3(2, 192, 2), blk, 0, stream>>>(
                xc, xc, 256, wq, nullptr, qc, nullptr, 256, 256, 1, minfo, 0);
            // k|v from side1 (old) -> kc/vc side1
            lft_mfma_gemm<<<dim3(4, 192, 1), blk, 0, stream>>>(
                xc, xc, 256, wk, kc, nullptr, vc, 512, 256, 4, minfo, 1);
            hipMemsetAsync(kvb, 0, (2 * 524288 + 2 * 16384) * 4, stream);
            lft_kv_kernel<<<dim3(KV_NCH, 8, 64), blk, 0, stream>>>(kc, vc, cmeta, kvb, ksb, 1);
            lft_msg_kernel<<<dim3(MSG_NCH, 8, 8), blk, 0, stream>>>(qc, kvb, ksb, cmeta, msgc, 0, 1);
            lft_gemm_ln<<<dim3(768, 1, 1), blk, 0, stream>>>(
                msgc, msgc, 256, wm, 256, g1p, b1p,
                nullptr, nullptr, gl, minfo, nullptr, msgc, 0);
            lft_mfma_gemm<<<dim3(4, 192, 1), blk, 0, stream>>>(
                xc, msgc, 256, w1, nullptr, hid, nullptr, 512, 512, 2, minfo, 0);
            lft_gemm_ln<<<dim3(768, 1, 1), blk, 0, stream>>>(
                hid, hid, 512, w2, 512, g2p, b2p,
                rc, last ? nullptr : rc, gl, minfo, last ? out : nullptr, xc, 0);
            // ---- side1 attends UPDATED side0 ----
            lft_mfma_gemm<<<dim3(4, 192, 1), blk, 0, stream>>>(
                xc, xc, 256, wk, kc, nullptr, vc, 512, 256, 4, minfo, 0);
            hipMemsetAsync(kvb, 0, (2 * 524288 + 2 * 16384) * 4, stream);
            lft_kv_kernel<<<dim3(KV_NCH, 8, 64), blk, 0, stream>>>(kc, vc, cmeta, kvb, ksb, 0);
            lft_msg_kernel<<<dim3(MSG_NCH, 8, 8), blk, 0, stream>>>(qc, kvb, ksb, cmeta, msgc, 1, 0);
            lft_gemm_ln<<<dim3(768, 1, 1), blk, 0, stream>>>(
                msgc, msgc, 256, wm, 256, g1p, b1p,
                nullptr, nullptr, gl, minfo, nullptr, msgc, 1);
            lft_mfma_gemm<<<dim3(4, 192, 1), blk, 0, stream>>>(
                xc, msgc, 256, w1, nullptr, hid, nullptr, 512, 512, 2, minfo, 1);
            lft_gemm_ln<<<dim3(768, 1, 1), blk, 0, stream>>>(
                hid, hid, 512, w2, 512, g2p, b2p,
                rc, last ? nullptr : rc, gl, minfo, last ? out : nullptr,
                last ? nullptr : xc, 1);
        }
    }
}

// Round 11
// 1448.894 us; speedup vs baseline: 1.9200x; 1.0070x over previous
//
#include <hip/hip_runtime.h>
#include <math.h>

#define NPROTO 8
#define KV_NCH 4
#define MSG_NCH 8
#define CAP 24576L            // compact rows per side (Mv ~= 19200 +- ~200)

typedef __attribute__((ext_vector_type(8))) short short8;
typedef __attribute__((ext_vector_type(4))) float floatx4;

static __device__ __forceinline__ ushort f2b(float f) {
    unsigned u = __builtin_bit_cast(unsigned, f);
    unsigned r = (u + 0x7fffu + ((u >> 16) & 1u)) >> 16;
    return (ushort)r;
}

static __device__ __forceinline__ float b2f(ushort u) {
    return __builtin_bit_cast(float, (unsigned)u << 16);
}

static __device__ __forceinline__ float elu1(float v) {
    return v > 0.f ? v + 1.f : __expf(v);
}

// async 16B global -> LDS (linear dest: wave base + lane*16B)
#define GLOAD16(gp, lp) __builtin_amdgcn_global_load_lds( \
    (const __attribute__((address_space(1))) void*)(gp),  \
    (__attribute__((address_space(3))) void*)(lp), 16, 0, 0)

// full drain + barrier (gemm_ln's proven 2-phase structure)
#define WAIT_BAR() asm volatile("s_waitcnt vmcnt(0) lgkmcnt(0)\n\ts_barrier" ::: "memory")
// counted waits (mfma_gemm 3-buffer pipeline; 4 loads/thread/tile)
#define VMWAIT(N) asm volatile("s_waitcnt vmcnt(" #N ")" ::: "memory")
#define BAR() __builtin_amdgcn_s_barrier()

// swizzle of the 16B-group index within a 32-col bf16 row (4 groups/row)
static __device__ __forceinline__ int swz(int r) { return (r >> 1) & 3; }

// ---------------- prototype projection / argmax-class kernel ----------------
__global__ __launch_bounds__(256) void lft_class_kernel(
    const float* __restrict__ f0wo, const float* __restrict__ f1wo,
    const int* __restrict__ mask0, const int* __restrict__ mask1,
    const float* __restrict__ proto,
    float* out, int* cls0, int* cls1)
{
    __shared__ float pr[2048];          // proto [8][256]
    __shared__ float tile[128][68];     // [token][ch chunk], stride 68
    __shared__ float sm[128][8];
    int t = threadIdx.x;
    *(float4*)&pr[t * 4]        = *(const float4*)&proto[t * 4];
    *(float4*)&pr[1024 + t * 4] = *(const float4*)&proto[1024 + t * 4];
    long tok0 = (long)blockIdx.x * 128;
    const float* fsrc; const int* msrc; float* fpout; float* clsout; int* clsarr; long tbase;
    if (tok0 < 38400) {
        tbase = tok0; fsrc = f0wo; msrc = mask0;
        fpout = out + 19737600L; clsout = out + 19660800L; clsarr = cls0;
    } else {
        tbase = tok0 - 38400; fsrc = f1wo; msrc = mask1;
        fpout = out + 20044800L; clsout = out + 19699200L; clsarr = cls1;
    }
    int tok = t & 127, half = t >> 7;
    float s[4] = {};
    int r0 = t >> 4;            // 0..15
    int c4 = (t & 15) << 2;     // 0..60
    for (int ct = 0; ct < 4; ct++) {
        __syncthreads();
#pragma unroll
        for (int rr = 0; rr < 8; rr++) {
            int row = rr * 16 + r0;
            float4 v = *(const float4*)&fsrc[(tbase + row) * 256 + ct * 64 + c4];
            *(float4*)&tile[row][c4] = v;
        }
        __syncthreads();
#pragma unroll
        for (int cc = 0; cc < 16; cc++) {
            float4 f = *(const float4*)&tile[tok][cc << 2];
#pragma unroll
            for (int p = 0; p < 4; p++) {
                float4 pv = *(const float4*)&pr[(half * 4 + p) * 256 + ct * 64 + (cc << 2)];
                s[p] += f.x * pv.x + f.y * pv.y + f.z * pv.z + f.w * pv.w;
            }
        }
    }
#pragma unroll
    for (int p = 0; p < 4; p++) {
        fpout[(tbase + tok) * 8 + half * 4 + p] = s[p];
        sm[tok][half * 4 + p] = s[p];
    }
    __syncthreads();
    if (t < 128) {
        int best = 0; float bv = sm[t][0];
#pragma unroll
        for (int p = 1; p < 8; p++) { if (sm[t][p] > bv) { bv = sm[t][p]; best = p; } }
        clsout[tbase + t] = (float)best;
        clsarr[tbase + t] = msrc[tbase + t] ? best : -1;
    }
}

// ---------------- copy ONLY invalid-token rows of feat into out --------------
__global__ __launch_bounds__(256) void lft_invcopy_kernel(
    const float* __restrict__ f0, const float* __restrict__ f1,
    const int* __restrict__ cls0, const int* __restrict__ cls1,
    float* out)
{
    int w = blockIdx.x * 4 + (threadIdx.x >> 6);   // 0..4799
    int lane = threadIdx.x & 63;
    for (long row = w; row < 76800; row += 4800) {
        int side = row >= 38400;
        long r = row - (long)side * 38400;
        int c = side ? cls1[r] : cls0[r];
        if (c < 0) {
            const float* src = side ? f1 : f0;
            float4 v = *(const float4*)&src[r * 256 + lane * 4];
            *(float4*)&out[(long)side * 9830400L + r * 256 + lane * 4] = v;
        }
    }
}

// ---------------- per-(L,b) class counts -> meta {base,cnt} ------------------
__global__ __launch_bounds__(256) void lft_count_kernel(
    const int* __restrict__ cls0, const int* __restrict__ cls1, int* meta)
{
    int g = blockIdx.x; int L = g >> 3, b = g & 7;
    const int* cls = (L ? cls1 : cls0) + b * 4800;
    int* mt = meta + (L * 8 + b) * 16;
    __shared__ int cnt[8];
    int t = threadIdx.x;
    if (t < 8) cnt[t] = 0;
    __syncthreads();
    for (int tok = t; tok < 4800; tok += 256) {
        int c = cls[tok];
        if (c >= 0) atomicAdd(&cnt[c], 1);
    }
    __syncthreads();
    if (t == 0) {
        int s = 0;
        for (int c = 0; c < 8; c++) { mt[c * 2] = s; mt[c * 2 + 1] = cnt[c]; s += cnt[c]; }
    }
}

// ---------------- cross-batch scan: minfo (Mv, boff) + compact cmeta ---------
__global__ __launch_bounds__(256) void lft_scan_kernel(
    const int* __restrict__ meta, int* minfo, int* cmeta)
{
    int t = threadIdx.x;
    __shared__ int nb[16];
    if (t < 16) {
        int s = 0;
        for (int c = 0; c < 8; c++) s += meta[t * 16 + c * 2 + 1];
        nb[t] = s;
    }
    __syncthreads();
    if (t == 0) {
        int off = 0;
        for (int b = 0; b < 8; b++) { minfo[4 + b] = off; off += nb[b]; }
        minfo[2] = off; minfo[0] = (off + 127) & ~127;
        off = 0;
        for (int b = 0; b < 8; b++) { minfo[12 + b] = off; off += nb[8 + b]; }
        minfo[3] = off; minfo[1] = (off + 127) & ~127;
    }
    __syncthreads();
    if (t < 128) {
        int L = t >> 6, b = (t >> 3) & 7, c = t & 7;
        cmeta[t * 2]     = minfo[4 + L * 8 + b] + meta[(L * 8 + b) * 16 + c * 2];
        cmeta[t * 2 + 1] = meta[(L * 8 + b) * 16 + c * 2 + 1];
    }
}

// ---------------- place valid tokens into compact gather lists ---------------
__global__ __launch_bounds__(256) void lft_place_kernel(
    const int* __restrict__ cls0, const int* __restrict__ cls1,
    const int* __restrict__ cmeta, int* gl)
{
    int g = blockIdx.x; int L = g >> 3, b = g & 7;
    const int* cls = (L ? cls1 : cls0) + b * 4800;
    int* glp = gl + L * CAP;
    __shared__ int pos[8];
    int t = threadIdx.x;
    if (t < 8) pos[t] = cmeta[(L * 64 + b * 8 + t) * 2];
    __syncthreads();
    for (int tok = t; tok < 4800; tok += 256) {
        int c = cls[tok];
        if (c >= 0) { int p = atomicAdd(&pos[c], 1); glp[p] = b * 4800 + tok; }
    }
}

// ---------------- gather-cast: compact bf16 x + compact fp32 resid -----------
__global__ __launch_bounds__(256) void lft_gcast_kernel(
    const float* __restrict__ f0, const float* __restrict__ f1,
    const int* __restrict__ gl, const int* __restrict__ minfo,
    ushort* xc, float* rc)
{
    int blk = blockIdx.x;
    int side = blk >= 600 ? 1 : 0;
    int i0 = (blk - side * 600) * 4 + (threadIdx.x >> 6);
    int mv = minfo[2 + side];
    const int* glp = gl + side * CAP;
    const float* f = side ? f1 : f0;
    ushort* xcp = xc + side * CAP * 256;
    float* rcp = rc + side * CAP * 256;
    int lane = threadIdx.x & 63;
    for (int i = i0; i < mv; i += 2400) {
        long src = (long)glp[i] * 256 + lane * 4;
        float4 v = *(const float4*)&f[src];
        long dst = (long)i * 256 + lane * 4;
        *(float4*)&rcp[dst] = v;
        ushort4 u; u.x = f2b(v.x); u.y = f2b(v.y); u.z = f2b(v.z); u.w = f2b(v.w);
        *(ushort4*)&xcp[dst] = u;
    }
}

// ---------------- weight convert + transpose: Wt[n*K+k] = bf16(W[k*N+n]) ----
__global__ __launch_bounds__(256) void lft_wconv_kernel(
    const float* W0, const float* W1p, const float* W2p, const float* W3p,
    int K, int N, int nTypes, ushort* dst)
{
    int z = blockIdx.z;
    int li = z / nTypes, mi = z % nTypes;
    const float* srcs[4] = {W0, W1p, W2p, W3p};
    const float* src = srcs[mi] + (size_t)li * K * N;
    ushort* outp = dst + (size_t)z * K * N;
    __shared__ float tile[32][33];
    int k0 = blockIdx.x * 32, n0 = blockIdx.y * 32;
    int t = threadIdx.x;
    int r = t >> 3, c4 = (t & 7) << 2;
    float4 v = *(const float4*)&src[(size_t)(k0 + r) * N + n0 + c4];
    tile[r][c4] = v.x; tile[r][c4 + 1] = v.y; tile[r][c4 + 2] = v.z; tile[r][c4 + 3] = v.w;
    __syncthreads();
    ushort4 o;
    o.x = f2b(tile[c4 + 0][r]);
    o.y = f2b(tile[c4 + 1][r]);
    o.z = f2b(tile[c4 + 2][r]);
    o.w = f2b(tile[c4 + 3][r]);
    *(ushort4*)&outp[(size_t)(n0 + r) * K + k0 + c4] = o;
}

// ---------------- bf16 MFMA GEMM over COMPACT rows, side = blockIdx.z --------
// 3-buffer counted-vmcnt pipeline (tile t+2 issued; wait leaves 2 tiles in
// flight -> HBM latency overlaps 2 compute phases). 128x128 tile, 4 waves,
// LDS 48KB (3 blocks/CU).
// act: 0 none, 1 elu+1, 2 relu; act 3 qkv N=768 (q bf16 / k bf16 / v bf16);
// act 4 kv N=512 (k bf16 / v bf16). k,v buffers are ushort (passed via Cf/Cv).
__global__ __launch_bounds__(256) void lft_mfma_gemm(
    const ushort* __restrict__ A0b, const ushort* __restrict__ A1b, int kSplit,
    const ushort* __restrict__ Wt,
    float* Cf, ushort* Cb, float* Cv, int N, int K, int act,
    const int* __restrict__ minfo, int side0)
{
    __shared__ ushort As[3][128 * 32];
    __shared__ ushort Bs[3][128 * 32];
    int side = side0 + blockIdx.z;
    int m0 = blockIdx.y << 7;
    if (m0 >= minfo[side]) return;
    const ushort* A0 = A0b + (long)side * CAP * kSplit;
    const ushort* A1 = A1b + (long)side * CAP * (K - kSplit);
    long so256 = (long)side * CAP * 256;
    long soN = (long)side * CAP * N;
    int t = threadIdx.x;
    int n0 = blockIdx.x << 7;
    int wv = t >> 6, lane = t & 63;
    int wm = wv >> 1, wn = wv & 1;
    int l16 = lane & 15, quad = lane >> 4;
    floatx4 acc[4][4] = {};

    int lrow = lane >> 2;
    int lcg = lane & 3;

    auto stage = [&](int buf, int k0) {
        const ushort* Asrc; int kcol, ldA;
        if (k0 < kSplit) { Asrc = A0; kcol = k0;          ldA = kSplit; }
        else             { Asrc = A1; kcol = k0 - kSplit; ldA = K - kSplit; }
        ushort* Ab = &As[buf][0];
        ushort* Bb = &Bs[buf][0];
#pragma unroll
        for (int s = 0; s < 2; s++) {
            int r = s * 64 + wv * 16 + lrow;
            int cgA = (lcg ^ swz(r)) << 3;
            GLOAD16(&Asrc[(size_t)(m0 + r) * ldA + kcol + cgA], &Ab[(s * 64 + wv * 16) * 32]);
            GLOAD16(&Wt[(size_t)(n0 + r) * K + k0 + cgA], &Bb[(s * 64 + wv * 16) * 32]);
        }
    };

    auto compute = [&](int buf) {
        const ushort* Ab = &As[buf][0];
        const ushort* Bb = &Bs[buf][0];
        short8 af[4], bfr[4];
#pragma unroll
        for (int i = 0; i < 4; i++) {
            int rA = wm * 64 + i * 16 + l16;
            int rB = wn * 64 + i * 16 + l16;
            af[i]  = *(const short8*)&Ab[rA * 32 + ((quad ^ swz(rA)) << 3)];
            bfr[i] = *(const short8*)&Bb[rB * 32 + ((quad ^ swz(rB)) << 3)];
        }
        __builtin_amdgcn_s_setprio(1);
#pragma unroll
        for (int i = 0; i < 4; i++)
#pragma unroll
            for (int j = 0; j < 4; j++)
                acc[i][j] = __builtin_amdgcn_mfma_f32_16x16x32_bf16(af[i], bfr[j], acc[i][j], 0, 0, 0);
        __builtin_amdgcn_s_setprio(0);
    };

    int nt = K >> 5;               // 8 or 16
    stage(0, 0);
    stage(1, 32);
    int cur = 0;
    for (int tt = 0; tt < nt; ++tt) {
        if (tt + 2 < nt) {
            int nb = cur + 2; if (nb >= 3) nb -= 3;
            stage(nb, (tt + 2) << 5);
            VMWAIT(8);             // tile tt done; tt+1, tt+2 in flight
        } else if (tt + 2 == nt) {
            VMWAIT(4);
        } else {
            VMWAIT(0);
        }
        BAR();
        compute(cur);
        if (tt + 1 < nt) BAR();
        cur = cur + 1 == 3 ? 0 : cur + 1;
    }

#pragma unroll
    for (int i = 0; i < 4; i++) {
#pragma unroll
        for (int j = 0; j < 4; j++) {
#pragma unroll
            for (int r = 0; r < 4; r++) {
                float v = acc[i][j][r];
                long row = m0 + wm * 64 + i * 16 + quad * 4 + r;
                int col = n0 + wn * 64 + j * 16 + l16;
                if (act == 3) {
                    if (col < 256)      Cb[so256 + row * 256 + col] = f2b(elu1(v));
                    else if (col < 512) ((ushort*)Cf)[so256 + row * 256 + col - 256] = f2b(elu1(v));
                    else                ((ushort*)Cv)[so256 + row * 256 + col - 512] = f2b(v);
                } else if (act == 4) {
                    if (col < 256) ((ushort*)Cf)[so256 + row * 256 + col] = f2b(elu1(v));
                    else           ((ushort*)Cv)[so256 + row * 256 + col - 256] = f2b(v);
                } else {
                    if (act == 1)      v = elu1(v);
                    else if (act == 2) v = fmaxf(v, 0.f);
                    if (Cf) Cf[soN + row * N + col] = v;
                    if (Cb) Cb[soN + row * N + col] = f2b(v);
                }
            }
        }
    }
}

// ---------------- fused GEMM (N=256) + row-LN over COMPACT rows -------------
// M=32 tile (grid.x=768 per side, early-exit); side = side0 + blockIdx.z.
// Proven 2-phase drain pipeline (unchanged from R10).
__global__ __launch_bounds__(256) void lft_gemm_ln(
    const ushort* __restrict__ A0b, const ushort* __restrict__ A1b, int kSplit,
    const ushort* __restrict__ Wt, int K,
    const float* __restrict__ g, const float* __restrict__ bb,
    const float* __restrict__ rcInB, float* rcOutB,
    const int* __restrict__ glB, const int* __restrict__ minfo,
    float* outScB, ushort* __restrict__ outBB, int side0)
{
    __shared__ ushort As[2][32 * 32];
    __shared__ ushort Bs[2][256 * 32];
    __shared__ float gs[256], bs[256];
    __shared__ float psum[4][32], psq[4][32];
    int side = side0 + blockIdx.z;
    long m0 = (long)blockIdx.x << 5;
    if (m0 >= minfo[side]) return;
    const ushort* A0 = A0b + (long)side * CAP * kSplit;
    const ushort* A1 = A1b + (long)side * CAP * (K - kSplit);
    long so = (long)side * CAP * 256;
    int t = threadIdx.x;
    int wv = t >> 6, lane = t & 63;
    int l16 = lane & 15, quad = lane >> 4;
    gs[t] = g[t]; bs[t] = bb[t];
    floatx4 acc[2][4] = {};

    int lrow = lane >> 2;
    int lcg = lane & 3;

    auto stage = [&](int buf, int k0) {
        const ushort* Asrc; int kcol, ldA;
        if (k0 < kSplit) { Asrc = A0; kcol = k0;          ldA = kSplit; }
        else             { Asrc = A1; kcol = k0 - kSplit; ldA = K - kSplit; }
        if (wv < 2) {
            int r = wv * 16 + lrow;
            int cgA = (lcg ^ swz(r)) << 3;
            GLOAD16(&Asrc[(m0 + r) * ldA + kcol + cgA], &As[buf][(wv * 16) * 32]);
        }
#pragma unroll
        for (int s = 0; s < 4; s++) {
            int r = s * 64 + wv * 16 + lrow;
            int cgB = (lcg ^ swz(r)) << 3;
            GLOAD16(&Wt[(size_t)r * K + k0 + cgB], &Bs[buf][(s * 64 + wv * 16) * 32]);
        }
    };

    int nt = K >> 5;
    stage(0, 0);
    WAIT_BAR();
    int cur = 0;
    for (int tt = 0; tt < nt; ++tt) {
        if (tt + 1 < nt) stage(cur ^ 1, (tt + 1) << 5);
        const ushort* Ab = &As[cur][0];
        const ushort* Bb = &Bs[cur][0];
        short8 af[2], bfr[4];
#pragma unroll
        for (int i = 0; i < 2; i++) {
            int rA = i * 16 + l16;
            af[i] = *(const short8*)&Ab[rA * 32 + ((quad ^ swz(rA)) << 3)];
        }
#pragma unroll
        for (int j = 0; j < 4; j++) {
            int rB = wv * 64 + j * 16 + l16;
            bfr[j] = *(const short8*)&Bb[rB * 32 + ((quad ^ swz(rB)) << 3)];
        }
#pragma unroll
        for (int i = 0; i < 2; i++)
#pragma unroll
            for (int j = 0; j < 4; j++)
                acc[i][j] = __builtin_amdgcn_mfma_f32_16x16x32_bf16(af[i], bfr[j], acc[i][j], 0, 0, 0);
        if (tt + 1 < nt) { WAIT_BAR(); cur ^= 1; }
    }
#pragma unroll
    for (int i = 0; i < 2; i++) {
#pragma unroll
        for (int r = 0; r < 4; r++) {
            float s = 0.f, q = 0.f;
#pragma unroll
            for (int j = 0; j < 4; j++) { float v = acc[i][j][r]; s += v; q += v * v; }
#pragma unroll
            for (int o = 8; o >= 1; o >>= 1) {
                s += __shfl_xor(s, o, 64);
                q += __shfl_xor(q, o, 64);
            }
            if (l16 == 0) {
                int row = i * 16 + quad * 4 + r;
                psum[wv][row] = s; psq[wv][row] = q;
            }
        }
    }
    __syncthreads();
    if (t < 32) {
        float s = psum[0][t] + psum[1][t] + psum[2][t] + psum[3][t];
        float q = psq[0][t] + psq[1][t] + psq[2][t] + psq[3][t];
        float mean = s * (1.0f / 256.0f);
        float var = q * (1.0f / 256.0f) - mean * mean;
        psum[0][t] = mean;
        psq[0][t] = rsqrtf(var + 1e-5f);
    }
    __syncthreads();
    int mvE = minfo[2 + side];
    const float* rcIn = rcInB ? rcInB + so : nullptr;
    float* rcOut = rcOutB ? rcOutB + so : nullptr;
    const int* glp = glB + side * CAP;
    float* outSc = outScB ? outScB + (long)side * 9830400L : nullptr;
    ushort* outB = outBB ? outBB + so : nullptr;
#pragma unroll
    for (int i = 0; i < 2; i++) {
#pragma unroll
        for (int r = 0; r < 4; r++) {
            int rloc = i * 16 + quad * 4 + r;
            long grow = m0 + rloc;
            float mean = psum[0][rloc], rstd = psq[0][rloc];
#pragma unroll
            for (int j = 0; j < 4; j++) {
                int col = wv * 64 + j * 16 + l16;
                float y = (acc[i][j][r] - mean) * rstd * gs[col] + bs[col];
                if (rcIn) y += rcIn[grow * 256 + col];
                if (rcOut) rcOut[grow * 256 + col] = y;
                if (outSc && grow < mvE) outSc[(long)glp[grow] * 256 + col] = y;
                if (outB) outB[grow * 256 + col] = f2b(y);
            }
        }
    }
}

// ---------------- per-class KV / Ksum reduction (compact, bf16 inputs) -------
__global__ __launch_bounds__(256) void lft_kv_kernel(
    const ushort* __restrict__ kcB, const ushort* __restrict__ vcB,
    const int* __restrict__ cmetaB,
    float* kvbB, float* ksbB, int sideSrc0)
{
    int side = sideSrc0 + (blockIdx.z >> 6);
    int zz = blockIdx.z & 63;
    int chunk = blockIdx.x, c = blockIdx.y;
    int b = zz >> 3, h = zz & 7;
    const int* cmeta = cmetaB + side * 128;
    int cstart = cmeta[(b * 8 + c) * 2], n = cmeta[(b * 8 + c) * 2 + 1];
    int per = (n + KV_NCH - 1) / KV_NCH;
    int s0 = chunk * per;
    int s1 = min(s0 + per, n);
    if (s0 >= s1) return;
    const ushort* phik = kcB + (long)side * CAP * 256;
    const ushort* vmat = vcB + (long)side * CAP * 256;
    float* kv = kvbB + (long)side * 524288;
    float* ksum = ksbB + (long)side * 16384;
    int t = threadIdx.x;
    __shared__ float kb[8][32];
    __shared__ float vb[8][32];
    int od = t >> 3, oe = (t & 7) << 2;
    int lt = t >> 5, ld = t & 31;
    float a0 = 0.f, a1 = 0.f, a2 = 0.f, a3 = 0.f, ak = 0.f;
    for (int s = s0; s < s1; s += 8) {
        float kval = 0.f, vval = 0.f;
        if (s + lt < s1) {
            long bse = (long)(cstart + s + lt) * 256 + h * 32 + ld;
            kval = b2f(phik[bse]);
            vval = b2f(vmat[bse]);
        }
        __syncthreads();
        kb[lt][ld] = kval;
        vb[lt][ld] = vval;
        __syncthreads();
#pragma unroll
        for (int j = 0; j < 8; j++) {
            float kd = kb[j][od];
            float4 vv = *(const float4*)&vb[j][oe];
            a0 += kd * vv.x; a1 += kd * vv.y; a2 += kd * vv.z; a3 += kd * vv.w;
            ak += kd;
        }
    }
    float* dst = kv + (((long)(b * NPROTO + c) * 8 + h) << 10) + od * 32 + oe;
    atomicAdd(dst + 0, a0);
    atomicAdd(dst + 1, a1);
    atomicAdd(dst + 2, a2);
    atomicAdd(dst + 3, a3);
    if ((t & 7) == 0)
        atomicAdd(ksum + (((long)(b * NPROTO + c) * 8 + h) << 5) + od, ak);
}

// ---------------- msg via MFMA over compact rows; kv fragments from fp32 -----
__global__ __launch_bounds__(256) void lft_msg_kernel(
    const ushort* __restrict__ qcB, const float* __restrict__ kvbB,
    const float* __restrict__ ksbB, const int* __restrict__ cmetaB,
    ushort* __restrict__ msgcB, int sideX0, int sideKV0)
{
    int add = blockIdx.z >> 3, b = blockIdx.z & 7;
    int sideX = sideX0 + add, sideKV = sideKV0 + add;
    int chunk = blockIdx.x, c = blockIdx.y;
    const int* cmeta = cmetaB + sideX * 128;
    int cstart = cmeta[(b * 8 + c) * 2], n = cmeta[(b * 8 + c) * 2 + 1];
    int per = (n + MSG_NCH - 1) / MSG_NCH;
    int s0 = chunk * per, s1 = min(s0 + per, n);
    if (s0 >= s1) return;
    const ushort* pq = qcB + (long)sideX * CAP * 256;
    ushort* msg = msgcB + (long)sideX * CAP * 256;
    int t = threadIdx.x;
    int wave = t >> 6, lane = t & 63;
    int l16 = lane & 15, quad = lane >> 4;
    int bc = b * 8 + c;
    short8 bfr[2][3];
#pragma unroll
    for (int hh = 0; hh < 2; hh++) {
        int h = wave * 2 + hh;
        const float* kvsrc = kvbB + (long)sideKV * 524288 + ((long)bc * 8 + h) * 1024;
        const float* kssrc = ksbB + (long)sideKV * 16384 + ((long)bc * 8 + h) * 32;
#pragma unroll
        for (int nt = 0; nt < 2; nt++)
#pragma unroll
            for (int j = 0; j < 8; j++)
                bfr[hh][nt][j] = (short)f2b(kvsrc[(quad * 8 + j) * 32 + nt * 16 + l16]);
#pragma unroll
        for (int j = 0; j < 8; j++)
            bfr[hh][2][j] = (l16 == 0) ? (short)f2b(kssrc[quad * 8 + j]) : (short)0;
    }
    for (int s = s0; s < s1; s += 16) {
        long rowA = cstart + min(s + l16, s1 - 1);
#pragma unroll
        for (int hh = 0; hh < 2; hh++) {
            int h = wave * 2 + hh;
            short8 a = *(const short8*)&pq[rowA * 256 + h * 32 + quad * 8];
            floatx4 n0 = {}, n1 = {}, dd = {};
            n0 = __builtin_amdgcn_mfma_f32_16x16x32_bf16(a, bfr[hh][0], n0, 0, 0, 0);
            n1 = __builtin_amdgcn_mfma_f32_16x16x32_bf16(a, bfr[hh][1], n1, 0, 0, 0);
            dd = __builtin_amdgcn_mfma_f32_16x16x32_bf16(a, bfr[hh][2], dd, 0, 0, 0);
#pragma unroll
            for (int r = 0; r < 4; r++) {
                int rowi = s + quad * 4 + r;
                float den = __shfl(dd[r], lane & 48, 64);
                float inv = 1.f / (den + 1e-6f);
                if (rowi < s1) {
                    long base = (long)(cstart + rowi) * 256 + h * 32;
                    msg[base + l16]      = f2b(n0[r] * inv);
                    msg[base + 16 + l16] = f2b(n1[r] * inv);
                }
            }
        }
    }
}

extern "C" void kernel_launch(void* const* d_in, const int* in_sizes, int n_in,
                              void* d_out, int out_size, void* d_ws, size_t ws_size,
                              hipStream_t stream)
{
    (void)in_sizes; (void)n_in; (void)out_size; (void)ws_size;
    const float* feat0 = (const float*)d_in[0];
    const float* feat1 = (const float*)d_in[1];
    const int*   mask0 = (const int*)d_in[2];
    const int*   mask1 = (const int*)d_in[3];
    const float* f0wo  = (const float*)d_in[4];
    const float* f1wo  = (const float*)d_in[5];
    const float* proto = (const float*)d_in[6];
    const float* Wq = (const float*)d_in[7];
    const float* Wk = (const float*)d_in[8];
    const float* Wv = (const float*)d_in[9];
    const float* Wm = (const float*)d_in[10];
    const float* W1 = (const float*)d_in[11];
    const float* W2 = (const float*)d_in[12];
    const float* g1 = (const float*)d_in[13];
    const float* b1 = (const float*)d_in[14];
    const float* g2 = (const float*)d_in[15];
    const float* b2 = (const float*)d_in[16];
    float* out = (float*)d_out;
    float* ws = (float*)d_ws;

    // ---- workspace layout (side-strided compact buffers, CAP rows/side) ----
    const long FSZ = 9830400L;
    float* rc = ws;                               // 2*CAP*256 f   (50.3MB)
    ushort* kc = (ushort*)(rc + 2 * CAP * 256);   // 2*CAP*256 us  (25.2MB) bf16
    ushort* vc = kc + 2 * CAP * 256;              // 2*CAP*256 us  bf16
    ushort* hid = vc + 2 * CAP * 256;             // 2*CAP*512 us  (50.3MB)
    ushort* xc   = hid + 2 * CAP * 512;
    ushort* msgc = xc + 2 * CAP * 256;
    ushort* qc   = msgc + 2 * CAP * 256;
    ushort* wb   = qc + 2 * CAP * 256;
    ushort* wb1  = wb + 16 * 65536;
    ushort* wb2  = wb1 + 4 * 262144;
    float* kvb = (float*)(wb2 + 4 * 131072);      // 2*524288 f
    float* ksb = kvb + 2 * 524288;                // 2*16384 f
    int* cls0 = (int*)(ksb + 2 * 16384);
    int* cls1 = cls0 + 38400;
    int* gl   = cls1 + 38400;                     // 2*CAP ints
    int* meta = gl + 2 * CAP;
    int* minfo = meta + 256;
    int* cmeta = minfo + 20;

    lft_wconv_kernel<<<dim3(8, 8, 16), 256, 0, stream>>>(Wq, Wk, Wv, Wm, 256, 256, 4, wb);
    lft_wconv_kernel<<<dim3(16, 16, 4), 256, 0, stream>>>(W1, W1, W1, W1, 512, 512, 1, wb1);
    lft_wconv_kernel<<<dim3(16, 8, 4), 256, 0, stream>>>(W2, W2, W2, W2, 512, 256, 1, wb2);
    hipMemcpyAsync(out + 20352000L, proto, 2048 * 4, hipMemcpyDeviceToDevice, stream);
    lft_class_kernel<<<600, 256, 0, stream>>>(f0wo, f1wo, mask0, mask1, proto,
                                              out, cls0, cls1);
    lft_invcopy_kernel<<<1200, 256, 0, stream>>>(feat0, feat1, cls0, cls1, out);
    lft_count_kernel<<<16, 256, 0, stream>>>(cls0, cls1, meta);
    lft_scan_kernel<<<1, 256, 0, stream>>>(meta, minfo, cmeta);
    lft_place_kernel<<<16, 256, 0, stream>>>(cls0, cls1, cmeta, gl);
    lft_gcast_kernel<<<1200, 256, 0, stream>>>(feat0, feat1, gl, minfo, xc, rc);

    dim3 blk(256);
    for (int li = 0; li < 4; li++) {
        const ushort* wq = wb + (size_t)(li * 4 + 0) * 65536;   // [wq|wk|wv|wm]
        const ushort* wk = wb + (size_t)(li * 4 + 1) * 65536;
        const ushort* wm = wb + (size_t)(li * 4 + 3) * 65536;
        const ushort* w1 = wb1 + (size_t)li * 262144;
        const ushort* w2 = wb2 + (size_t)li * 131072;
        const float* g1p = g1 + li * 256; const float* b1p = b1 + li * 256;
        const float* g2p = g2 + li * 256; const float* b2p = b2 + li * 256;
        bool last = (li == 3);

        if ((li & 1) == 0) {
            // ---- self-self, both sides combined (z=2) ----
            lft_mfma_gemm<<<dim3(6, 192, 2), blk, 0, stream>>>(
                xc, xc, 256, wq, (float*)kc, qc, (float*)vc, 768, 256, 3, minfo, 0);
            hipMemsetAsync(kvb, 0, (2 * 524288 + 2 * 16384) * 4, stream);
            lft_kv_kernel<<<dim3(KV_NCH, 8, 128), blk, 0, stream>>>(kc, vc, cmeta, kvb, ksb, 0);
            lft_msg_kernel<<<dim3(MSG_NCH, 8, 16), blk, 0, stream>>>(qc, kvb, ksb, cmeta, msgc, 0, 0);
            lft_gemm_ln<<<dim3(768, 1, 2), blk, 0, stream>>>(
                msgc, msgc, 256, wm, 256, g1p, b1p,
                nullptr, nullptr, gl, minfo, nullptr, msgc, 0);
            lft_mfma_gemm<<<dim3(4, 192, 2), blk, 0, stream>>>(
                xc, msgc, 256, w1, nullptr, hid, nullptr, 512, 512, 2, minfo, 0);
            lft_gemm_ln<<<dim3(768, 1, 2), blk, 0, stream>>>(
                hid, hid, 512, w2, 512, g2p, b2p,
                rc, rc, gl, minfo, nullptr, xc, 0);
        } else {
            // ---- cross-self: q for both sides from OLD features ----
            lft_mfma_gemm<<<dim3(2, 192, 2), blk, 0, stream>>>(
                xc, xc, 256, wq, nullptr, qc, nullptr, 256, 256, 1, minfo, 0);
            // k|v from side1 (old) -> kc/vc side1
            lft_mfma_gemm<<<dim3(4, 192, 1), blk, 0, stream>>>(
                xc, xc, 256, wk, (float*)kc, nullptr, (float*)vc, 512, 256, 4, minfo, 1);
            hipMemsetAsync(kvb, 0, (2 * 524288 + 2 * 16384) * 4, stream);
            lft_kv_kernel<<<dim3(KV_NCH, 8, 64), blk, 0, stream>>>(kc, vc, cmeta, kvb, ksb, 1);
            lft_msg_kernel<<<dim3(MSG_NCH, 8, 8), blk, 0, stream>>>(qc, kvb, ksb, cmeta, msgc, 0, 1);
            lft_gemm_ln<<<dim3(768, 1, 1), blk, 0, stream>>>(
                msgc, msgc, 256, wm, 256, g1p, b1p,
                nullptr, nullptr, gl, minfo, nullptr, msgc, 0);
            lft_mfma_gemm<<<dim3(4, 192, 1), blk, 0, stream>>>(
                xc, msgc, 256, w1, nullptr, hid, nullptr, 512, 512, 2, minfo, 0);
            lft_gemm_ln<<<dim3(768, 1, 1), blk, 0, stream>>>(
                hid, hid, 512, w2, 512, g2p, b2p,
                rc, last ? nullptr : rc, gl, minfo, last ? out : nullptr, xc, 0);
            // ---- side1 attends UPDATED side0 ----
            lft_mfma_gemm<<<dim3(4, 192, 1), blk, 0, stream>>>(
                xc, xc, 256, wk, (float*)kc, nullptr, (float*)vc, 512, 256, 4, minfo, 0);
            hipMemsetAsync(kvb, 0, (2 * 524288 + 2 * 16384) * 4, stream);
            lft_kv_kernel<<<dim3(KV_NCH, 8, 64), blk, 0, stream>>>(kc, vc, cmeta, kvb, ksb, 0);
            lft_msg_kernel<<<dim3(MSG_NCH, 8, 8), blk, 0, stream>>>(qc, kvb, ksb, cmeta, msgc, 1, 0);
            lft_gemm_ln<<<dim3(768, 1, 1), blk, 0, stream>>>(
                msgc, msgc, 256, wm, 256, g1p, b1p,
                nullptr, nullptr, gl, minfo, nullptr, msgc, 1);
            lft_mfma_gemm<<<dim3(4, 192, 1), blk, 0, stream>>>(
                xc, msgc, 256, w1, nullptr, hid, nullptr, 512, 512, 2, minfo, 1);
            lft_gemm_ln<<<dim3(768, 1, 1), blk, 0, stream>>>(
                hid, hid, 512, w2, 512, g2p, b2p,
                rc, last ? nullptr : rc, gl, minfo, last ? out : nullptr,
                last ? nullptr : xc, 1);
        }
    }
}